// Round 2
// baseline (770.057 us; speedup 1.0000x reference)
//
#include <hip/hip_runtime.h>
#include <cstdint>
#include <cstddef>

// Dims (fixed by the problem)
#define BB 8
#define CC 128
#define C3 384
#define HH 64
#define H2 32
#define NPIX 1024   // 32*32
#define N4 4096     // 64*64
#define NHD 8
#define HD 16

typedef _Float16 h2f __attribute__((ext_vector_type(2)));

union HU { uint32_t u; h2f h; };
union U4H { uint4 u; h2f h[4]; };

__device__ inline h2f pkrtz(float a, float b) {
  return __builtin_bit_cast(h2f, __builtin_amdgcn_cvt_pkrtz(a, b));
}

__device__ inline h2f shflh(h2f v, int m) {
  HU x; x.h = v;
  x.u = (uint32_t)__shfl_xor((int)x.u, m);
  return x.h;
}

// ---------------- K1: Haar DWT ----------------
__global__ __launch_bounds__(256) void k_dwt(const float* __restrict__ x,
                                             float* __restrict__ ll,
                                             float* __restrict__ high) {
  int idx = blockIdx.x * 256 + threadIdx.x;   // B*C*32*32 = 1,048,576
  int w = idx & 31, h = (idx >> 5) & 31, c = (idx >> 10) & 127, b = idx >> 17;
  const float* xp = x + ((size_t)(b * CC + c) * HH + 2 * h) * HH + 2 * w;
  float x1 = xp[0];
  float x2 = xp[HH];
  float x3 = xp[1];
  float x4 = xp[HH + 1];
  int n = h * H2 + w;
  ll[(size_t)(b * CC + c) * NPIX + n]              = 0.5f * ( x1 + x2 + x3 + x4);
  high[((size_t)b * C3 + c) * NPIX + n]            = 0.5f * (-x1 - x2 + x3 + x4);
  high[((size_t)b * C3 + CC + c) * NPIX + n]       = 0.5f * (-x1 + x2 - x3 + x4);
  high[((size_t)b * C3 + 2 * CC + c) * NPIX + n]   = 0.5f * ( x1 - x2 - x3 + x4);
}

// ---------------- conv1x1: register GEMV; OPT outs x P pixels per thread ----
// grid = (Npix/(256*P), Cout/OPT, B). OPT small (4-8) keeps VGPR low and
// grids large (>=1024 blocks) so latency is hidden by occupancy.
template <int CIN, int P, int OPT>
__global__ __launch_bounds__(256) void k_conv1x1(const float* __restrict__ in,
                                                 const float* __restrict__ w,
                                                 float* __restrict__ out,
                                                 int Cout, int Npix) {
  int tid = threadIdx.x;
  int n0 = (blockIdx.x * 256 + tid) * P;
  int o0 = blockIdx.y * OPT;
  int b = blockIdx.z;
  const float* inb = in + (size_t)b * CIN * Npix + n0;
  const float* wb = w + (size_t)o0 * CIN;
  float acc[OPT][P];
#pragma unroll
  for (int o = 0; o < OPT; ++o)
#pragma unroll
    for (int p = 0; p < P; ++p) acc[o][p] = 0.f;

  for (int c0 = 0; c0 < CIN; c0 += 8) {
#pragma unroll
    for (int c = 0; c < 8; ++c) {
      float vv[P];
      const float* ip = inb + (size_t)(c0 + c) * Npix;
      if constexpr (P == 4) {
        float4 t = *(const float4*)ip;
        vv[0] = t.x; vv[1] = t.y; vv[2] = t.z; vv[3] = t.w;
      } else if constexpr (P == 2) {
        float2 t = *(const float2*)ip;
        vv[0] = t.x; vv[1] = t.y;
      } else {
        vv[0] = ip[0];
      }
#pragma unroll
      for (int o = 0; o < OPT; ++o) {
        float wc = wb[(size_t)o * CIN + c0 + c];   // uniform -> s_load
#pragma unroll
        for (int p = 0; p < P; ++p) acc[o][p] = fmaf(wc, vv[p], acc[o][p]);
      }
    }
  }
  size_t ob = ((size_t)b * Cout + o0) * Npix + n0;
#pragma unroll
  for (int o = 0; o < OPT; ++o) {
    float* op = out + ob + (size_t)o * Npix;
    if constexpr (P == 4) {
      *(float4*)op = make_float4(acc[o][0], acc[o][1], acc[o][2], acc[o][3]);
    } else if constexpr (P == 2) {
      *(float2*)op = make_float2(acc[o][0], acc[o][1]);
    } else {
      op[0] = acc[o][0];
    }
  }
}

// ---------------- K2b: split qkv + l2norm q,k; emit packed fp16 ----------------
__global__ __launch_bounds__(256) void k_qkvnorm(const float* __restrict__ qkv,
                                                 uint4* __restrict__ qh,
                                                 uint4* __restrict__ kh,
                                                 uint4* __restrict__ vh) {
  int idx = blockIdx.x * 256 + threadIdx.x;  // 65536 = B*NH*NPIX
  int n = idx & 1023, h = (idx >> 10) & 7, b = idx >> 13;
  const float* base = qkv + ((size_t)b * C3 + h * HD) * NPIX + n;
  float q[HD], k[HD], vv[HD];
  float sq = 0.f, sk = 0.f;
#pragma unroll
  for (int d = 0; d < HD; ++d) {
    q[d] = base[(size_t)d * NPIX];
    k[d] = base[(size_t)(CC + d) * NPIX];
    vv[d] = base[(size_t)(2 * CC + d) * NPIX];
    sq += q[d] * q[d];
    sk += k[d] * k[d];
  }
  float rq = 1.f / fmaxf(sqrtf(sq), 1e-12f);
  float rk = 1.f / fmaxf(sqrtf(sk), 1e-12f);
#pragma unroll
  for (int g = 0; g < 2; ++g) {
    U4H pq, pk, pv;
#pragma unroll
    for (int d = 0; d < 4; ++d) {
      int e = g * 8 + 2 * d;
      pq.h[d] = pkrtz(q[e] * rq, q[e + 1] * rq);
      pk.h[d] = pkrtz(k[e] * rk, k[e + 1] * rk);
      pv.h[d] = pkrtz(vv[e], vv[e + 1]);
    }
    qh[(size_t)idx * 2 + g] = pq.u;
    kh[(size_t)idx * 2 + g] = pk.u;
    vh[(size_t)idx * 2 + g] = pv.u;
  }
}

// ---------------- K3: sparse top-k attention, fp16-packed ----------------
// 2 q-rows per wave + __launch_bounds__(256,8): targets <=64 VGPR so the
// kernel sits in the 8-waves/SIMD occupancy bracket (latency chains in the
// bisect/fold phases are hidden by wave interleaving, not ILP).
__global__ __launch_bounds__(256, 8) void k_attn(const uint32_t* __restrict__ qh,
                                                 const uint4* __restrict__ kh,
                                                 const uint4* __restrict__ vh,
                                                 float* __restrict__ attn_out) {
  __shared__ uint32_t q_lds[64];
  int tid = threadIdx.x;
  int lane = tid & 63;
  int wave = tid >> 6;
  int blk = blockIdx.x;            // 8192 blocks; 128 blocks per (b,h)
  int row0 = blk * 8;
  int bh = blk >> 7;
  if (tid < 64) q_lds[tid] = qh[(size_t)blk * 64 + tid];
  __syncthreads();
  // q pre-scaled by hd^-0.5 = 0.25 (power of 2 -> exact in fp16)
  h2f qs2[2][8];
  const h2f qsc = (h2f){(_Float16)0.25f, (_Float16)0.25f};
  const uint32_t* qw = &q_lds[wave * 16];
#pragma unroll
  for (int q = 0; q < 2; ++q)
#pragma unroll
    for (int d = 0; d < 8; ++d) {
      HU u; u.u = qw[q * 8 + d];
      qs2[q][d] = u.h * qsc;
    }

  const uint4* kb = kh + (size_t)bh * 2048;   // 1024 rows * 2 uint4
  const uint4* vb = vh + (size_t)bh * 2048;

  // ---- phase 1: scores (fdot2, fp32 accum), packed into half2 ----
  uint4 kbuf[2][2];
#pragma unroll
  for (int i = 0; i < 2; ++i) {
    const uint4* kr = kb + (size_t)((i * 64 + lane) * 2);
    kbuf[i][0] = kr[0];
    kbuf[i][1] = kr[1];
  }
  h2f s2[2][8];
  float se[2];
#pragma unroll
  for (int i = 0; i < 16; ++i) {
    U4H u0, u1;
    u0.u = kbuf[i & 1][0];
    u1.u = kbuf[i & 1][1];
    if (i + 2 < 16) {
      const uint4* kr = kb + (size_t)(((i + 2) * 64 + lane) * 2);
      kbuf[i & 1][0] = kr[0];
      kbuf[i & 1][1] = kr[1];
    }
    h2f k2[8];
#pragma unroll
    for (int d = 0; d < 4; ++d) { k2[d] = u0.h[d]; k2[4 + d] = u1.h[d]; }
#pragma unroll
    for (int q = 0; q < 2; ++q) {
      float acc = 0.f;
#pragma unroll
      for (int d = 0; d < 8; ++d)
        acc = __builtin_amdgcn_fdot2(qs2[q][d], k2[d], acc, false);
      if (i & 1) s2[q][i >> 1] = pkrtz(se[q], acc);
      else       se[q] = acc;
    }
  }

  // ---- issue first V rows now; the bisect below hides their latency ----
  uint4 vbuf[2][2];
#pragma unroll
  for (int i = 0; i < 2; ++i) {
    const uint4* vr = vb + (size_t)((i * 64 + lane) * 2);
    vbuf[i][0] = vr[0];
    vbuf[i][1] = vr[1];
  }
  asm volatile("" ::: "memory");

  // ---- bisect for 512th-largest: f16 compare + ballot (SALU adds) ----
  float lo[2], hi[2];
  _Float16 hlo[2];
#pragma unroll
  for (int q = 0; q < 2; ++q) { lo[q] = -0.26f; hi[q] = 0.26f; hlo[q] = (_Float16)(-0.26f); }
  for (int it = 0; it < 12; ++it) {
#pragma unroll
    for (int q = 0; q < 2; ++q) {
      float mid = 0.5f * (lo[q] + hi[q]);
      _Float16 hm = (_Float16)mid;
      int c = 0;
#pragma unroll
      for (int j = 0; j < 8; ++j) {
        h2f t = s2[q][j];
        c += __popcll(__ballot(t[0] >= hm));
        c += __popcll(__ballot(t[1] >= hm));
      }
      if (c >= 512) { lo[q] = mid; hlo[q] = hm; } else hi[q] = mid;
    }
  }

  // ---- masked softmax in place (s2 -> unnormalized p, packed) ----
  float inv[2];
#pragma unroll
  for (int q = 0; q < 2; ++q) {
    float sum = 0.f;
#pragma unroll
    for (int j = 0; j < 8; ++j) {
      h2f t = s2[q][j];
      float p0 = (t[0] >= hlo[q]) ? __expf((float)t[0]) : 0.f;
      float p1 = (t[1] >= hlo[q]) ? __expf((float)t[1]) : 0.f;
      sum += p0 + p1;
      s2[q][j] = pkrtz(p0, p1);
    }
#pragma unroll
    for (int off = 32; off > 0; off >>= 1) sum += __shfl_xor(sum, off);
    inv[q] = 1.f / sum;
  }

  // ---- phase 2: AV (packed fp16 fma), depth-2 prefetch ring ----
  h2f ov2[2][8];
#pragma unroll
  for (int q = 0; q < 2; ++q)
#pragma unroll
    for (int d = 0; d < 8; ++d) ov2[q][d] = (h2f)0;
#pragma unroll
  for (int i = 0; i < 16; ++i) {
    U4H u0, u1;
    u0.u = vbuf[i & 1][0];
    u1.u = vbuf[i & 1][1];
    if (i + 2 < 16) {
      const uint4* vr = vb + (size_t)(((i + 2) * 64 + lane) * 2);
      vbuf[i & 1][0] = vr[0];
      vbuf[i & 1][1] = vr[1];
    }
    h2f v2[8];
#pragma unroll
    for (int d = 0; d < 4; ++d) { v2[d] = u0.h[d]; v2[4 + d] = u1.h[d]; }
#pragma unroll
    for (int q = 0; q < 2; ++q) {
      h2f t = s2[q][i >> 1];
      _Float16 pf = (i & 1) ? t[1] : t[0];
      h2f pp = (h2f){pf, pf};
#pragma unroll
      for (int d = 0; d < 8; ++d)
        ov2[q][d] = __builtin_elementwise_fma(pp, v2[d], ov2[q][d]);
    }
  }

  // ---- fold-transpose reduce (high/low split): lane L -> dim bitrev4(L) ----
  int b = bh >> 3, h = bh & 7;
  int dim = ((lane & 1) << 3) | ((lane & 2) << 1) | ((lane & 4) >> 1) | ((lane & 8) >> 3);
#pragma unroll
  for (int q = 0; q < 2; ++q) {
    bool m0 = (lane & 1) != 0;
    h2f B1[4];
#pragma unroll
    for (int p = 0; p < 4; ++p) {
      h2f r0 = shflh(ov2[q][p], 1);
      h2f r1 = shflh(ov2[q][p + 4], 1);
      h2f a0 = ov2[q][p] + r0;
      h2f a1 = ov2[q][p + 4] + r1;
      B1[p] = m0 ? a1 : a0;
    }
    bool m1 = (lane & 2) != 0;
    h2f B2[2];
#pragma unroll
    for (int p = 0; p < 2; ++p) {
      h2f r0 = shflh(B1[p], 2);
      h2f r1 = shflh(B1[p + 2], 2);
      h2f a0 = B1[p] + r0;
      h2f a1 = B1[p + 2] + r1;
      B2[p] = m1 ? a1 : a0;
    }
    bool m2 = (lane & 4) != 0;
    {
      h2f r0 = shflh(B2[0], 4);
      h2f r1 = shflh(B2[1], 4);
      h2f a0 = B2[0] + r0;
      h2f a1 = B2[1] + r1;
      B2[0] = m2 ? a1 : a0;
    }
    h2f r = shflh(B2[0], 8);
    h2f t = B2[0] + r;
    bool m3 = (lane & 8) != 0;
    float wf = m3 ? (float)t[1] : (float)t[0];
    wf += __shfl_xor(wf, 16);
    wf += __shfl_xor(wf, 32);
    if (lane < 16) {
      int n = (row0 + wave * 2 + q) & 1023;
      attn_out[((size_t)(b * CC + h * HD + dim) * NPIX) + n] = wf * inv[q];
    }
  }
}

// ---------------- K5a: depthwise 3x3 SAME conv ----------------
__global__ __launch_bounds__(256) void k_dwconv(const float* __restrict__ in,
                                                const float* __restrict__ w,
                                                float* __restrict__ out) {
  int n = blockIdx.x * 256 + threadIdx.x;
  int c = blockIdx.y, b = blockIdx.z;
  int i = n >> 5, j = n & 31;
  const float* inb = in + ((size_t)b * C3 + c) * NPIX;
  const float* wc = w + c * 9;
  float acc = 0.f;
#pragma unroll
  for (int di = -1; di <= 1; ++di) {
    int ii = i + di;
    if (ii < 0 || ii > 31) continue;
#pragma unroll
    for (int dj = -1; dj <= 1; ++dj) {
      int jj = j + dj;
      if (jj < 0 || jj > 31) continue;
      acc += inb[ii * 32 + jj] * wc[(di + 1) * 3 + (dj + 1)];
    }
  }
  out[((size_t)b * C3 + c) * NPIX + n] = acc;
}

// ---------------- GroupNorm (32 groups) + fused epilogue, float4, 512 thr ----
// Reduce: wave shfl-reduce -> 8-entry LDS -> broadcast (2 barriers).
template <int ACT, bool HAS_RES>
__global__ __launch_bounds__(512) void k_gn(const float* __restrict__ x,
                                            const float* __restrict__ res,
                                            float* __restrict__ out,
                                            const float* __restrict__ gamma,
                                            const float* __restrict__ beta,
                                            const float* __restrict__ alpha_ptr,
                                            float alpha_const,
                                            int chPerGroup, int Npix, int nshift) {
  int g = blockIdx.x & 31, b = blockIdx.x >> 5;
  int Cout = 32 * chPerGroup;
  int elems = chPerGroup * Npix;
  int nv = elems >> 2;
  size_t base = ((size_t)b * Cout + g * chPerGroup) * Npix;
  const float4* xv = (const float4*)(x + base);
  int tid = threadIdx.x;
  float s = 0.f, s2 = 0.f;
  for (int i = tid; i < nv; i += 512) {
    float4 v = xv[i];
    s += v.x + v.y + v.z + v.w;
    s2 += v.x * v.x + v.y * v.y + v.z * v.z + v.w * v.w;
  }
#pragma unroll
  for (int off = 32; off > 0; off >>= 1) {
    s += __shfl_xor(s, off);
    s2 += __shfl_xor(s2, off);
  }
  __shared__ float ls[8], ls2[8];
  int wv = tid >> 6, ln = tid & 63;
  if (ln == 0) { ls[wv] = s; ls2[wv] = s2; }
  __syncthreads();
  float st = 0.f, s2t = 0.f;
#pragma unroll
  for (int i = 0; i < 8; ++i) { st += ls[i]; s2t += ls2[i]; }
  float inv_n = 1.f / (float)elems;
  float mean = st * inv_n;
  float var = s2t * inv_n - mean * mean;
  float rstd = rsqrtf(var + 1e-6f);
  float a = alpha_ptr ? alpha_ptr[0] : alpha_const;
  const float4* rv = (const float4*)(res + base);
  float4* ov = (float4*)(out + base);
  int cshift = nshift - 2;
  for (int i = tid; i < nv; i += 512) {
    float4 v = xv[i];
    int cc = g * chPerGroup + (i >> cshift);
    float gm = gamma[cc], bt = beta[cc];
    float r[4] = {v.x, v.y, v.z, v.w};
#pragma unroll
    for (int p = 0; p < 4; ++p) {
      float gnv = (r[p] - mean) * rstd * gm + bt;
      if (ACT == 1)      r[p] = gnv / (1.f + __expf(-gnv));
      else if (ACT == 2) r[p] = 0.5f * gnv * (1.f + erff(gnv * 0.70710678118654752f));
      else               r[p] = gnv;
    }
    float4 o;
    if (HAS_RES) {
      float4 rr = rv[i];
      o = make_float4(rr.x + a * r[0], rr.y + a * r[1], rr.z + a * r[2], rr.w + a * r[3]);
    } else {
      o = make_float4(r[0], r[1], r[2], r[3]);
    }
    ov[i] = o;
  }
}

// ---------------- K6: IWT + residual ----------------
__global__ __launch_bounds__(256) void k_iwt(const float* __restrict__ x,
                                             const float* __restrict__ s1,
                                             const float* __restrict__ hout,
                                             float* __restrict__ out) {
  int idx = blockIdx.x * 256 + threadIdx.x;  // B*C*32*32
  int w = idx & 31, h = (idx >> 5) & 31, c = (idx >> 10) & 127, b = idx >> 17;
  int n = h * 32 + w;
  float ll = s1[(size_t)(b * CC + c) * NPIX + n];
  float lh = hout[((size_t)b * C3 + c) * NPIX + n];
  float hl = hout[((size_t)b * C3 + CC + c) * NPIX + n];
  float hh = hout[((size_t)b * C3 + 2 * CC + c) * NPIX + n];
  float va = ll - lh - hl + hh;
  float vb = ll - lh + hl - hh;
  float vc = ll + lh - hl - hh;
  float vd = ll + lh + hl + hh;
  size_t xb = ((size_t)(b * CC + c) * HH + 2 * h) * HH + 2 * w;
  out[xb]          = x[xb]          + 0.1f * va;
  out[xb + 1]      = x[xb + 1]      + 0.1f * vc;
  out[xb + HH]     = x[xb + HH]     + 0.1f * vb;
  out[xb + HH + 1] = x[xb + HH + 1] + 0.1f * vd;
}

extern "C" void kernel_launch(void* const* d_in, const int* in_sizes, int n_in,
                              void* d_out, int out_size, void* d_ws, size_t ws_size,
                              hipStream_t stream) {
  const float* x         = (const float*)d_in[0];
  const float* qkv_w     = (const float*)d_in[1];
  const float* proj_w    = (const float*)d_in[2];
  const float* attn_gn_g = (const float*)d_in[3];
  const float* attn_gn_b = (const float*)d_in[4];
  const float* he_dw_w   = (const float*)d_in[5];
  const float* he_gn1_g  = (const float*)d_in[6];
  const float* he_gn1_b  = (const float*)d_in[7];
  const float* he_pw_w   = (const float*)d_in[8];
  const float* he_gn2_g  = (const float*)d_in[9];
  const float* he_gn2_b  = (const float*)d_in[10];
  const float* alpha     = (const float*)d_in[11];
  const float* ffn_w1    = (const float*)d_in[12];
  const float* ffn_gn1_g = (const float*)d_in[13];
  const float* ffn_gn1_b = (const float*)d_in[14];
  const float* ffn_w2    = (const float*)d_in[15];
  const float* ffn_gn2_g = (const float*)d_in[16];
  const float* ffn_gn2_b = (const float*)d_in[17];
  float* out = (float*)d_out;

  float* ws = (float*)d_ws;
  float* ll   = ws;              // 1,048,576
  float* high = ws + 1048576;    // 3,145,728
  float* qkv  = ws + 4194304;    // 3,145,728 ; reused as y1
  float* qnkv = ws + 7340032;    // 3,145,728 ; qh|kh|vh (fp16) ; reused as pw/h_out
  float* atto = ws + 10485760;   // 1,048,576
  float* proj = ws + 11534336;   // 1,048,576
  float* f1   = ws + 12582912;   // 8,388,608
  float* f3   = ws + 20971520;   // 4,194,304
  uint4* qh = (uint4*)qnkv;
  uint4* kh = (uint4*)(qnkv + 524288);
  uint4* vh = (uint4*)(qnkv + 1048576);
  float* y1 = qkv;
  float* pw = qnkv;

  // 1) DWT
  k_dwt<<<4096, 256, 0, stream>>>(x, ll, high);
  // 2) qkv = conv1x1(ll, qkv_w); split + l2norm -> packed fp16
  k_conv1x1<128, 1, 8><<<dim3(4, 48, 8), 256, 0, stream>>>(ll, qkv_w, qkv, 384, 1024);
  k_qkvnorm<<<256, 256, 0, stream>>>(qkv, qh, kh, vh);
  // 3) sparse attention (2 q-rows per wave, 8 waves/SIMD target)
  k_attn<<<8192, 256, 0, stream>>>((const uint32_t*)qh, kh, vh, atto);
  // 4) proj + groupnorm, s1 = ll + gn(proj)
  k_conv1x1<128, 1, 4><<<dim3(4, 32, 8), 256, 0, stream>>>(atto, proj_w, proj, 128, 1024);
  k_gn<0, true><<<256, 512, 0, stream>>>(proj, ll, proj, attn_gn_g, attn_gn_b,
                                         nullptr, 1.0f, 4, 1024, 10);
  // 5) high enhance
  k_dwconv<<<dim3(4, 384, 8), 256, 0, stream>>>(high, he_dw_w, y1);
  k_gn<1, false><<<256, 512, 0, stream>>>(y1, nullptr, y1, he_gn1_g, he_gn1_b,
                                          nullptr, 0.f, 12, 1024, 10);
  k_conv1x1<384, 1, 8><<<dim3(4, 48, 8), 256, 0, stream>>>(y1, he_pw_w, pw, 384, 1024);
  k_gn<0, true><<<256, 512, 0, stream>>>(pw, high, pw, he_gn2_g, he_gn2_b,
                                         alpha, 0.f, 12, 1024, 10);
  // 6) IWT + residual -> out
  k_iwt<<<4096, 256, 0, stream>>>(x, proj, pw, out);
  // 7) FFN
  k_conv1x1<128, 2, 8><<<dim3(8, 32, 8), 256, 0, stream>>>(out, ffn_w1, f1, 256, 4096);
  k_gn<2, false><<<256, 512, 0, stream>>>(f1, nullptr, f1, ffn_gn1_g, ffn_gn1_b,
                                          nullptr, 0.f, 8, 4096, 12);
  k_conv1x1<256, 2, 8><<<dim3(8, 16, 8), 256, 0, stream>>>(f1, ffn_w2, f3, 128, 4096);
  k_gn<0, true><<<256, 512, 0, stream>>>(f3, out, out, ffn_gn2_g, ffn_gn2_b,
                                         nullptr, 0.1f, 4, 4096, 12);
  (void)in_sizes; (void)n_in; (void)out_size; (void)ws_size;
}

// Round 3
// 457.599 us; speedup vs baseline: 1.6828x; 1.6828x over previous
//
#include <hip/hip_runtime.h>
#include <cstdint>
#include <cstddef>

// Dims (fixed by the problem)
#define BB 8
#define CC 128
#define C3 384
#define HH 64
#define H2 32
#define NPIX 1024   // 32*32
#define N4 4096     // 64*64
#define NHD 8
#define HD 16

typedef _Float16 h2f __attribute__((ext_vector_type(2)));

union HU { uint32_t u; h2f h; };
union U4H { uint4 u; h2f h[4]; };

__device__ inline h2f pkrtz(float a, float b) {
  return __builtin_bit_cast(h2f, __builtin_amdgcn_cvt_pkrtz(a, b));
}

__device__ inline h2f shflh(h2f v, int m) {
  HU x; x.h = v;
  x.u = (uint32_t)__shfl_xor((int)x.u, m);
  return x.h;
}

// DPP cross-lane exchanges: xor1 / xor2 inside each quad (pure VALU, no LDS)
__device__ inline h2f shflh_x1(h2f v) {
  HU x; x.h = v;
  x.u = (uint32_t)__builtin_amdgcn_update_dpp(0, (int)x.u, 0xB1, 0xf, 0xf, true); // quad_perm [1,0,3,2]
  return x.h;
}
__device__ inline h2f shflh_x2(h2f v) {
  HU x; x.h = v;
  x.u = (uint32_t)__builtin_amdgcn_update_dpp(0, (int)x.u, 0x4E, 0xf, 0xf, true); // quad_perm [2,3,0,1]
  return x.h;
}

// 64-lane sum -> scalar (lane 63), classic GCN DPP ladder; no SALU, no LDS.
__device__ inline int dpp_red_add_i32(int v) {
  int t;
  t = __builtin_amdgcn_update_dpp(0, v, 0x111, 0xf, 0xf, false); v += t; // row_shr:1
  t = __builtin_amdgcn_update_dpp(0, v, 0x112, 0xf, 0xf, false); v += t; // row_shr:2
  t = __builtin_amdgcn_update_dpp(0, v, 0x114, 0xf, 0xe, false); v += t; // row_shr:4
  t = __builtin_amdgcn_update_dpp(0, v, 0x118, 0xf, 0xc, false); v += t; // row_shr:8
  t = __builtin_amdgcn_update_dpp(0, v, 0x142, 0xa, 0xf, false); v += t; // row_bcast:15
  t = __builtin_amdgcn_update_dpp(0, v, 0x143, 0xc, 0xf, false); v += t; // row_bcast:31
  return __builtin_amdgcn_readlane(v, 63);
}

__device__ inline float dpp_red_add_f32(float x) {
  union FI { float f; int i; };
  FI a, t; a.f = x;
  t.i = __builtin_amdgcn_update_dpp(0, a.i, 0x111, 0xf, 0xf, false); a.f += t.f;
  t.i = __builtin_amdgcn_update_dpp(0, a.i, 0x112, 0xf, 0xf, false); a.f += t.f;
  t.i = __builtin_amdgcn_update_dpp(0, a.i, 0x114, 0xf, 0xe, false); a.f += t.f;
  t.i = __builtin_amdgcn_update_dpp(0, a.i, 0x118, 0xf, 0xc, false); a.f += t.f;
  t.i = __builtin_amdgcn_update_dpp(0, a.i, 0x142, 0xa, 0xf, false); a.f += t.f;
  t.i = __builtin_amdgcn_update_dpp(0, a.i, 0x143, 0xc, 0xf, false); a.f += t.f;
  FI r; r.i = __builtin_amdgcn_readlane(a.i, 63);
  return r.f;
}

// ---------------- K1: Haar DWT ----------------
__global__ __launch_bounds__(256) void k_dwt(const float* __restrict__ x,
                                             float* __restrict__ ll,
                                             float* __restrict__ high) {
  int idx = blockIdx.x * 256 + threadIdx.x;   // B*C*32*32 = 1,048,576
  int w = idx & 31, h = (idx >> 5) & 31, c = (idx >> 10) & 127, b = idx >> 17;
  const float* xp = x + ((size_t)(b * CC + c) * HH + 2 * h) * HH + 2 * w;
  float x1 = xp[0];
  float x2 = xp[HH];
  float x3 = xp[1];
  float x4 = xp[HH + 1];
  int n = h * H2 + w;
  ll[(size_t)(b * CC + c) * NPIX + n]              = 0.5f * ( x1 + x2 + x3 + x4);
  high[((size_t)b * C3 + c) * NPIX + n]            = 0.5f * (-x1 - x2 + x3 + x4);
  high[((size_t)b * C3 + CC + c) * NPIX + n]       = 0.5f * (-x1 + x2 - x3 + x4);
  high[((size_t)b * C3 + 2 * CC + c) * NPIX + n]   = 0.5f * ( x1 - x2 - x3 + x4);
}

// ---------------- conv1x1: register GEMV; OPT outs x P pixels per thread ----
template <int CIN, int P, int OPT>
__global__ __launch_bounds__(256) void k_conv1x1(const float* __restrict__ in,
                                                 const float* __restrict__ w,
                                                 float* __restrict__ out,
                                                 int Cout, int Npix) {
  int tid = threadIdx.x;
  int n0 = (blockIdx.x * 256 + tid) * P;
  int o0 = blockIdx.y * OPT;
  int b = blockIdx.z;
  const float* inb = in + (size_t)b * CIN * Npix + n0;
  const float* wb = w + (size_t)o0 * CIN;
  float acc[OPT][P];
#pragma unroll
  for (int o = 0; o < OPT; ++o)
#pragma unroll
    for (int p = 0; p < P; ++p) acc[o][p] = 0.f;

  for (int c0 = 0; c0 < CIN; c0 += 8) {
#pragma unroll
    for (int c = 0; c < 8; ++c) {
      float vv[P];
      const float* ip = inb + (size_t)(c0 + c) * Npix;
      if constexpr (P == 4) {
        float4 t = *(const float4*)ip;
        vv[0] = t.x; vv[1] = t.y; vv[2] = t.z; vv[3] = t.w;
      } else if constexpr (P == 2) {
        float2 t = *(const float2*)ip;
        vv[0] = t.x; vv[1] = t.y;
      } else {
        vv[0] = ip[0];
      }
#pragma unroll
      for (int o = 0; o < OPT; ++o) {
        float wc = wb[(size_t)o * CIN + c0 + c];   // uniform -> s_load
#pragma unroll
        for (int p = 0; p < P; ++p) acc[o][p] = fmaf(wc, vv[p], acc[o][p]);
      }
    }
  }
  size_t ob = ((size_t)b * Cout + o0) * Npix + n0;
#pragma unroll
  for (int o = 0; o < OPT; ++o) {
    float* op = out + ob + (size_t)o * Npix;
    if constexpr (P == 4) {
      *(float4*)op = make_float4(acc[o][0], acc[o][1], acc[o][2], acc[o][3]);
    } else if constexpr (P == 2) {
      *(float2*)op = make_float2(acc[o][0], acc[o][1]);
    } else {
      op[0] = acc[o][0];
    }
  }
}

// ---------------- K2b: split qkv + l2norm q,k; emit packed fp16 ----------------
__global__ __launch_bounds__(256) void k_qkvnorm(const float* __restrict__ qkv,
                                                 uint4* __restrict__ qh,
                                                 uint4* __restrict__ kh,
                                                 uint4* __restrict__ vh) {
  int idx = blockIdx.x * 256 + threadIdx.x;  // 65536 = B*NH*NPIX
  int n = idx & 1023, h = (idx >> 10) & 7, b = idx >> 13;
  const float* base = qkv + ((size_t)b * C3 + h * HD) * NPIX + n;
  float q[HD], k[HD], vv[HD];
  float sq = 0.f, sk = 0.f;
#pragma unroll
  for (int d = 0; d < HD; ++d) {
    q[d] = base[(size_t)d * NPIX];
    k[d] = base[(size_t)(CC + d) * NPIX];
    vv[d] = base[(size_t)(2 * CC + d) * NPIX];
    sq += q[d] * q[d];
    sk += k[d] * k[d];
  }
  float rq = 1.f / fmaxf(sqrtf(sq), 1e-12f);
  float rk = 1.f / fmaxf(sqrtf(sk), 1e-12f);
#pragma unroll
  for (int g = 0; g < 2; ++g) {
    U4H pq, pk, pv;
#pragma unroll
    for (int d = 0; d < 4; ++d) {
      int e = g * 8 + 2 * d;
      pq.h[d] = pkrtz(q[e] * rq, q[e + 1] * rq);
      pk.h[d] = pkrtz(k[e] * rk, k[e + 1] * rk);
      pv.h[d] = pkrtz(vv[e], vv[e + 1]);
    }
    qh[(size_t)idx * 2 + g] = pq.u;
    kh[(size_t)idx * 2 + g] = pk.u;
    vh[(size_t)idx * 2 + g] = pv.u;
  }
}

// ---------------- K3: sparse top-k attention, fp16-packed ----------------
// 4 q-rows/wave. Bisect counting moved off the (per-CU, shared) scalar ALU:
// per-lane VALU compare+add, DPP-tree reduce, one readlane -> ~3 SALU per
// (iter,q) instead of ~33. Softmax sum + fold xor1/xor2 also DPP.
__global__ __launch_bounds__(256) void k_attn(const uint32_t* __restrict__ qh,
                                              const uint4* __restrict__ kh,
                                              const uint4* __restrict__ vh,
                                              float* __restrict__ attn_out) {
  __shared__ uint32_t q_lds[128];
  int tid = threadIdx.x;
  int lane = tid & 63;
  int wave = tid >> 6;
  int blk = blockIdx.x;            // 4096 blocks; 64 blocks per (b,h)
  int row0 = blk * 16;
  int bh = blk >> 6;
  if (tid < 128) q_lds[tid] = qh[(size_t)blk * 128 + tid];
  __syncthreads();
  // q pre-scaled by hd^-0.5 = 0.25 (power of 2 -> exact in fp16)
  h2f qs2[4][8];
  const h2f qsc = (h2f){(_Float16)0.25f, (_Float16)0.25f};
  const uint32_t* qw = &q_lds[wave * 32];
#pragma unroll
  for (int q = 0; q < 4; ++q)
#pragma unroll
    for (int d = 0; d < 8; ++d) {
      HU u; u.u = qw[q * 8 + d];
      qs2[q][d] = u.h * qsc;
    }

  const uint4* kb = kh + (size_t)bh * 2048;   // 1024 rows * 2 uint4
  const uint4* vb = vh + (size_t)bh * 2048;

  // ---- phase 1: scores (fdot2, fp32 accum), depth-3 K prefetch ring ----
  uint4 kbuf[3][2];
#pragma unroll
  for (int i = 0; i < 3; ++i) {
    const uint4* kr = kb + (size_t)((i * 64 + lane) * 2);
    kbuf[i][0] = kr[0];
    kbuf[i][1] = kr[1];
  }
  h2f s2[4][8];
  float se[4];
#pragma unroll
  for (int i = 0; i < 16; ++i) {
    U4H u0, u1;
    u0.u = kbuf[i % 3][0];
    u1.u = kbuf[i % 3][1];
    if (i + 3 < 16) {
      const uint4* kr = kb + (size_t)(((i + 3) * 64 + lane) * 2);
      kbuf[i % 3][0] = kr[0];
      kbuf[i % 3][1] = kr[1];
    }
    h2f k2[8];
#pragma unroll
    for (int d = 0; d < 4; ++d) { k2[d] = u0.h[d]; k2[4 + d] = u1.h[d]; }
#pragma unroll
    for (int q = 0; q < 4; ++q) {
      float acc = 0.f;
#pragma unroll
      for (int d = 0; d < 8; ++d)
        acc = __builtin_amdgcn_fdot2(qs2[q][d], k2[d], acc, false);
      if (i & 1) s2[q][i >> 1] = pkrtz(se[q], acc);
      else       se[q] = acc;
    }
  }

  // ---- issue first V rows now; the bisect below hides their latency ----
  uint4 vbuf[3][2];
#pragma unroll
  for (int i = 0; i < 3; ++i) {
    const uint4* vr = vb + (size_t)((i * 64 + lane) * 2);
    vbuf[i][0] = vr[0];
    vbuf[i][1] = vr[1];
  }
  asm volatile("" ::: "memory");

  // ---- bisect for 512th-largest: per-lane VALU count + DPP reduce ----
  // (identical predicate/threshold lattice as the ballot/popc version)
  float lo[4], hi[4];
  _Float16 hlo[4];
#pragma unroll
  for (int q = 0; q < 4; ++q) { lo[q] = -0.26f; hi[q] = 0.26f; hlo[q] = (_Float16)(-0.26f); }
  for (int it = 0; it < 12; ++it) {
#pragma unroll
    for (int q = 0; q < 4; ++q) {
      float mid = 0.5f * (lo[q] + hi[q]);
      _Float16 hm = (_Float16)mid;
      int c = 0;
#pragma unroll
      for (int j = 0; j < 8; ++j) {
        h2f t = s2[q][j];
        c += (t[0] >= hm) ? 1 : 0;
        c += (t[1] >= hm) ? 1 : 0;
      }
      c = dpp_red_add_i32(c);   // uniform total across the wave
      if (c >= 512) { lo[q] = mid; hlo[q] = hm; } else hi[q] = mid;
    }
  }

  // ---- masked softmax in place (s2 -> unnormalized p, packed) ----
  float inv[4];
#pragma unroll
  for (int q = 0; q < 4; ++q) {
    float sum = 0.f;
#pragma unroll
    for (int j = 0; j < 8; ++j) {
      h2f t = s2[q][j];
      float p0 = (t[0] >= hlo[q]) ? __expf((float)t[0]) : 0.f;
      float p1 = (t[1] >= hlo[q]) ? __expf((float)t[1]) : 0.f;
      sum += p0 + p1;
      s2[q][j] = pkrtz(p0, p1);
    }
    float tot = dpp_red_add_f32(sum);  // uniform
    inv[q] = 1.f / tot;
  }

  // ---- phase 2: AV (packed fp16 fma), depth-3 prefetch ring ----
  h2f ov2[4][8];
#pragma unroll
  for (int q = 0; q < 4; ++q)
#pragma unroll
    for (int d = 0; d < 8; ++d) ov2[q][d] = (h2f)0;
#pragma unroll
  for (int i = 0; i < 16; ++i) {
    U4H u0, u1;
    u0.u = vbuf[i % 3][0];
    u1.u = vbuf[i % 3][1];
    if (i + 3 < 16) {
      const uint4* vr = vb + (size_t)(((i + 3) * 64 + lane) * 2);
      vbuf[i % 3][0] = vr[0];
      vbuf[i % 3][1] = vr[1];
    }
    h2f v2[8];
#pragma unroll
    for (int d = 0; d < 4; ++d) { v2[d] = u0.h[d]; v2[4 + d] = u1.h[d]; }
#pragma unroll
    for (int q = 0; q < 4; ++q) {
      h2f t = s2[q][i >> 1];
      _Float16 pf = (i & 1) ? t[1] : t[0];
      h2f pp = (h2f){pf, pf};
#pragma unroll
      for (int d = 0; d < 8; ++d)
        ov2[q][d] = __builtin_elementwise_fma(pp, v2[d], ov2[q][d]);
    }
  }

  // ---- fold-transpose reduce (high/low split): lane L -> dim bitrev4(L) ----
  int b = bh >> 3, h = bh & 7;
  int dim = ((lane & 1) << 3) | ((lane & 2) << 1) | ((lane & 4) >> 1) | ((lane & 8) >> 3);
#pragma unroll
  for (int q = 0; q < 4; ++q) {
    bool m0 = (lane & 1) != 0;
    h2f B1[4];
#pragma unroll
    for (int p = 0; p < 4; ++p) {
      h2f r0 = shflh_x1(ov2[q][p]);
      h2f r1 = shflh_x1(ov2[q][p + 4]);
      h2f a0 = ov2[q][p] + r0;
      h2f a1 = ov2[q][p + 4] + r1;
      B1[p] = m0 ? a1 : a0;
    }
    bool m1 = (lane & 2) != 0;
    h2f B2[2];
#pragma unroll
    for (int p = 0; p < 2; ++p) {
      h2f r0 = shflh_x2(B1[p]);
      h2f r1 = shflh_x2(B1[p + 2]);
      h2f a0 = B1[p] + r0;
      h2f a1 = B1[p + 2] + r1;
      B2[p] = m1 ? a1 : a0;
    }
    bool m2 = (lane & 4) != 0;
    {
      h2f r0 = shflh(B2[0], 4);
      h2f r1 = shflh(B2[1], 4);
      h2f a0 = B2[0] + r0;
      h2f a1 = B2[1] + r1;
      B2[0] = m2 ? a1 : a0;
    }
    h2f r = shflh(B2[0], 8);
    h2f t = B2[0] + r;
    bool m3 = (lane & 8) != 0;
    float wf = m3 ? (float)t[1] : (float)t[0];
    wf += __shfl_xor(wf, 16);
    wf += __shfl_xor(wf, 32);
    if (lane < 16) {
      int n = (row0 + wave * 4 + q) & 1023;
      attn_out[((size_t)(b * CC + h * HD + dim) * NPIX) + n] = wf * inv[q];
    }
  }
}

// ---------------- K5a: depthwise 3x3 SAME conv ----------------
__global__ __launch_bounds__(256) void k_dwconv(const float* __restrict__ in,
                                                const float* __restrict__ w,
                                                float* __restrict__ out) {
  int n = blockIdx.x * 256 + threadIdx.x;
  int c = blockIdx.y, b = blockIdx.z;
  int i = n >> 5, j = n & 31;
  const float* inb = in + ((size_t)b * C3 + c) * NPIX;
  const float* wc = w + c * 9;
  float acc = 0.f;
#pragma unroll
  for (int di = -1; di <= 1; ++di) {
    int ii = i + di;
    if (ii < 0 || ii > 31) continue;
#pragma unroll
    for (int dj = -1; dj <= 1; ++dj) {
      int jj = j + dj;
      if (jj < 0 || jj > 31) continue;
      acc += inb[ii * 32 + jj] * wc[(di + 1) * 3 + (dj + 1)];
    }
  }
  out[((size_t)b * C3 + c) * NPIX + n] = acc;
}

// ---------------- GroupNorm (32 groups) + fused epilogue, float4, 512 thr ----
template <int ACT, bool HAS_RES>
__global__ __launch_bounds__(512) void k_gn(const float* __restrict__ x,
                                            const float* __restrict__ res,
                                            float* __restrict__ out,
                                            const float* __restrict__ gamma,
                                            const float* __restrict__ beta,
                                            const float* __restrict__ alpha_ptr,
                                            float alpha_const,
                                            int chPerGroup, int Npix, int nshift) {
  int g = blockIdx.x & 31, b = blockIdx.x >> 5;
  int Cout = 32 * chPerGroup;
  int elems = chPerGroup * Npix;
  int nv = elems >> 2;
  size_t base = ((size_t)b * Cout + g * chPerGroup) * Npix;
  const float4* xv = (const float4*)(x + base);
  int tid = threadIdx.x;
  float s = 0.f, s2 = 0.f;
  for (int i = tid; i < nv; i += 512) {
    float4 v = xv[i];
    s += v.x + v.y + v.z + v.w;
    s2 += v.x * v.x + v.y * v.y + v.z * v.z + v.w * v.w;
  }
#pragma unroll
  for (int off = 32; off > 0; off >>= 1) {
    s += __shfl_xor(s, off);
    s2 += __shfl_xor(s2, off);
  }
  __shared__ float ls[8], ls2[8];
  int wv = tid >> 6, ln = tid & 63;
  if (ln == 0) { ls[wv] = s; ls2[wv] = s2; }
  __syncthreads();
  float st = 0.f, s2t = 0.f;
#pragma unroll
  for (int i = 0; i < 8; ++i) { st += ls[i]; s2t += ls2[i]; }
  float inv_n = 1.f / (float)elems;
  float mean = st * inv_n;
  float var = s2t * inv_n - mean * mean;
  float rstd = rsqrtf(var + 1e-6f);
  float a = alpha_ptr ? alpha_ptr[0] : alpha_const;
  const float4* rv = (const float4*)(res + base);
  float4* ov = (float4*)(out + base);
  int cshift = nshift - 2;
  for (int i = tid; i < nv; i += 512) {
    float4 v = xv[i];
    int cc = g * chPerGroup + (i >> cshift);
    float gm = gamma[cc], bt = beta[cc];
    float r[4] = {v.x, v.y, v.z, v.w};
#pragma unroll
    for (int p = 0; p < 4; ++p) {
      float gnv = (r[p] - mean) * rstd * gm + bt;
      if (ACT == 1)      r[p] = gnv / (1.f + __expf(-gnv));
      else if (ACT == 2) r[p] = 0.5f * gnv * (1.f + erff(gnv * 0.70710678118654752f));
      else               r[p] = gnv;
    }
    float4 o;
    if (HAS_RES) {
      float4 rr = rv[i];
      o = make_float4(rr.x + a * r[0], rr.y + a * r[1], rr.z + a * r[2], rr.w + a * r[3]);
    } else {
      o = make_float4(r[0], r[1], r[2], r[3]);
    }
    ov[i] = o;
  }
}

// ---------------- K6: IWT + residual ----------------
__global__ __launch_bounds__(256) void k_iwt(const float* __restrict__ x,
                                             const float* __restrict__ s1,
                                             const float* __restrict__ hout,
                                             float* __restrict__ out) {
  int idx = blockIdx.x * 256 + threadIdx.x;  // B*C*32*32
  int w = idx & 31, h = (idx >> 5) & 31, c = (idx >> 10) & 127, b = idx >> 17;
  int n = h * 32 + w;
  float ll = s1[(size_t)(b * CC + c) * NPIX + n];
  float lh = hout[((size_t)b * C3 + c) * NPIX + n];
  float hl = hout[((size_t)b * C3 + CC + c) * NPIX + n];
  float hh = hout[((size_t)b * C3 + 2 * CC + c) * NPIX + n];
  float va = ll - lh - hl + hh;
  float vb = ll - lh + hl - hh;
  float vc = ll + lh - hl - hh;
  float vd = ll + lh + hl + hh;
  size_t xb = ((size_t)(b * CC + c) * HH + 2 * h) * HH + 2 * w;
  out[xb]          = x[xb]          + 0.1f * va;
  out[xb + 1]      = x[xb + 1]      + 0.1f * vc;
  out[xb + HH]     = x[xb + HH]     + 0.1f * vb;
  out[xb + HH + 1] = x[xb + HH + 1] + 0.1f * vd;
}

extern "C" void kernel_launch(void* const* d_in, const int* in_sizes, int n_in,
                              void* d_out, int out_size, void* d_ws, size_t ws_size,
                              hipStream_t stream) {
  const float* x         = (const float*)d_in[0];
  const float* qkv_w     = (const float*)d_in[1];
  const float* proj_w    = (const float*)d_in[2];
  const float* attn_gn_g = (const float*)d_in[3];
  const float* attn_gn_b = (const float*)d_in[4];
  const float* he_dw_w   = (const float*)d_in[5];
  const float* he_gn1_g  = (const float*)d_in[6];
  const float* he_gn1_b  = (const float*)d_in[7];
  const float* he_pw_w   = (const float*)d_in[8];
  const float* he_gn2_g  = (const float*)d_in[9];
  const float* he_gn2_b  = (const float*)d_in[10];
  const float* alpha     = (const float*)d_in[11];
  const float* ffn_w1    = (const float*)d_in[12];
  const float* ffn_gn1_g = (const float*)d_in[13];
  const float* ffn_gn1_b = (const float*)d_in[14];
  const float* ffn_w2    = (const float*)d_in[15];
  const float* ffn_gn2_g = (const float*)d_in[16];
  const float* ffn_gn2_b = (const float*)d_in[17];
  float* out = (float*)d_out;

  float* ws = (float*)d_ws;
  float* ll   = ws;              // 1,048,576
  float* high = ws + 1048576;    // 3,145,728
  float* qkv  = ws + 4194304;    // 3,145,728 ; reused as y1
  float* qnkv = ws + 7340032;    // 3,145,728 ; qh|kh|vh (fp16) ; reused as pw/h_out
  float* atto = ws + 10485760;   // 1,048,576
  float* proj = ws + 11534336;   // 1,048,576
  float* f1   = ws + 12582912;   // 8,388,608
  float* f3   = ws + 20971520;   // 4,194,304
  uint4* qh = (uint4*)qnkv;
  uint4* kh = (uint4*)(qnkv + 524288);
  uint4* vh = (uint4*)(qnkv + 1048576);
  float* y1 = qkv;
  float* pw = qnkv;

  // 1) DWT
  k_dwt<<<4096, 256, 0, stream>>>(x, ll, high);
  // 2) qkv = conv1x1(ll, qkv_w); split + l2norm -> packed fp16
  k_conv1x1<128, 1, 8><<<dim3(4, 48, 8), 256, 0, stream>>>(ll, qkv_w, qkv, 384, 1024);
  k_qkvnorm<<<256, 256, 0, stream>>>(qkv, qh, kh, vh);
  // 3) sparse attention (4 q-rows per wave, fp16-packed state)
  k_attn<<<4096, 256, 0, stream>>>((const uint32_t*)qh, kh, vh, atto);
  // 4) proj + groupnorm, s1 = ll + gn(proj)
  k_conv1x1<128, 1, 4><<<dim3(4, 32, 8), 256, 0, stream>>>(atto, proj_w, proj, 128, 1024);
  k_gn<0, true><<<256, 512, 0, stream>>>(proj, ll, proj, attn_gn_g, attn_gn_b,
                                         nullptr, 1.0f, 4, 1024, 10);
  // 5) high enhance
  k_dwconv<<<dim3(4, 384, 8), 256, 0, stream>>>(high, he_dw_w, y1);
  k_gn<1, false><<<256, 512, 0, stream>>>(y1, nullptr, y1, he_gn1_g, he_gn1_b,
                                          nullptr, 0.f, 12, 1024, 10);
  k_conv1x1<384, 1, 8><<<dim3(4, 48, 8), 256, 0, stream>>>(y1, he_pw_w, pw, 384, 1024);
  k_gn<0, true><<<256, 512, 0, stream>>>(pw, high, pw, he_gn2_g, he_gn2_b,
                                         alpha, 0.f, 12, 1024, 10);
  // 6) IWT + residual -> out
  k_iwt<<<4096, 256, 0, stream>>>(x, proj, pw, out);
  // 7) FFN
  k_conv1x1<128, 2, 8><<<dim3(8, 32, 8), 256, 0, stream>>>(out, ffn_w1, f1, 256, 4096);
  k_gn<2, false><<<256, 512, 0, stream>>>(f1, nullptr, f1, ffn_gn1_g, ffn_gn1_b,
                                          nullptr, 0.f, 8, 4096, 12);
  k_conv1x1<256, 2, 8><<<dim3(8, 16, 8), 256, 0, stream>>>(f1, ffn_w2, f3, 128, 4096);
  k_gn<0, true><<<256, 512, 0, stream>>>(f3, out, out, ffn_gn2_g, ffn_gn2_b,
                                         nullptr, 0.1f, 4, 4096, 12);
  (void)in_sizes; (void)n_in; (void)out_size; (void)ws_size;
}

// Round 4
// 416.598 us; speedup vs baseline: 1.8484x; 1.0984x over previous
//
#include <hip/hip_runtime.h>
#include <cstdint>
#include <cstddef>

// Dims (fixed by the problem)
#define BB 8
#define CC 128
#define C3 384
#define HH 64
#define H2 32
#define NPIX 1024   // 32*32
#define N4 4096     // 64*64
#define NHD 8
#define HD 16

typedef _Float16 h2f __attribute__((ext_vector_type(2)));
typedef _Float16 h4f __attribute__((ext_vector_type(4)));
typedef float f4 __attribute__((ext_vector_type(4)));

union U4H { uint4 u; h2f h[4]; };
union H4U { h4f v; h2f h[2]; };

__device__ inline h2f pkrtz(float a, float b) {
  return __builtin_bit_cast(h2f, __builtin_amdgcn_cvt_pkrtz(a, b));
}

// ---------------- K1: Haar DWT ----------------
__global__ __launch_bounds__(256) void k_dwt(const float* __restrict__ x,
                                             float* __restrict__ ll,
                                             float* __restrict__ high) {
  int idx = blockIdx.x * 256 + threadIdx.x;   // B*C*32*32 = 1,048,576
  int w = idx & 31, h = (idx >> 5) & 31, c = (idx >> 10) & 127, b = idx >> 17;
  const float* xp = x + ((size_t)(b * CC + c) * HH + 2 * h) * HH + 2 * w;
  float x1 = xp[0];
  float x2 = xp[HH];
  float x3 = xp[1];
  float x4 = xp[HH + 1];
  int n = h * H2 + w;
  ll[(size_t)(b * CC + c) * NPIX + n]              = 0.5f * ( x1 + x2 + x3 + x4);
  high[((size_t)b * C3 + c) * NPIX + n]            = 0.5f * (-x1 - x2 + x3 + x4);
  high[((size_t)b * C3 + CC + c) * NPIX + n]       = 0.5f * (-x1 + x2 - x3 + x4);
  high[((size_t)b * C3 + 2 * CC + c) * NPIX + n]   = 0.5f * ( x1 - x2 - x3 + x4);
}

// ---------------- conv1x1: register GEMV; OPT outs x P pixels per thread ----
template <int CIN, int P, int OPT>
__global__ __launch_bounds__(256) void k_conv1x1(const float* __restrict__ in,
                                                 const float* __restrict__ w,
                                                 float* __restrict__ out,
                                                 int Cout, int Npix) {
  int tid = threadIdx.x;
  int n0 = (blockIdx.x * 256 + tid) * P;
  int o0 = blockIdx.y * OPT;
  int b = blockIdx.z;
  const float* inb = in + (size_t)b * CIN * Npix + n0;
  const float* wb = w + (size_t)o0 * CIN;
  float acc[OPT][P];
#pragma unroll
  for (int o = 0; o < OPT; ++o)
#pragma unroll
    for (int p = 0; p < P; ++p) acc[o][p] = 0.f;

  for (int c0 = 0; c0 < CIN; c0 += 8) {
#pragma unroll
    for (int c = 0; c < 8; ++c) {
      float vv[P];
      const float* ip = inb + (size_t)(c0 + c) * Npix;
      if constexpr (P == 4) {
        float4 t = *(const float4*)ip;
        vv[0] = t.x; vv[1] = t.y; vv[2] = t.z; vv[3] = t.w;
      } else if constexpr (P == 2) {
        float2 t = *(const float2*)ip;
        vv[0] = t.x; vv[1] = t.y;
      } else {
        vv[0] = ip[0];
      }
#pragma unroll
      for (int o = 0; o < OPT; ++o) {
        float wc = wb[(size_t)o * CIN + c0 + c];   // uniform -> s_load
#pragma unroll
        for (int p = 0; p < P; ++p) acc[o][p] = fmaf(wc, vv[p], acc[o][p]);
      }
    }
  }
  size_t ob = ((size_t)b * Cout + o0) * Npix + n0;
#pragma unroll
  for (int o = 0; o < OPT; ++o) {
    float* op = out + ob + (size_t)o * Npix;
    if constexpr (P == 4) {
      *(float4*)op = make_float4(acc[o][0], acc[o][1], acc[o][2], acc[o][3]);
    } else if constexpr (P == 2) {
      *(float2*)op = make_float2(acc[o][0], acc[o][1]);
    } else {
      op[0] = acc[o][0];
    }
  }
}

// ---------------- K2b: split qkv + l2norm q,k -> fp16; V -> transposed vt ----
// vt layout: [bh][dim(16)][1024] fp16 (A-fragment-friendly for phase 2 MFMA)
__global__ __launch_bounds__(256) void k_qkvnorm(const float* __restrict__ qkv,
                                                 uint4* __restrict__ qh,
                                                 uint4* __restrict__ kh,
                                                 uint16_t* __restrict__ vt) {
  __shared__ uint16_t lds_v[16 * 256];
  int tid = threadIdx.x;
  int idx = blockIdx.x * 256 + tid;  // 65536 = B*NH*NPIX
  int n = idx & 1023, h = (idx >> 10) & 7, b = idx >> 13;
  const float* base = qkv + ((size_t)b * C3 + h * HD) * NPIX + n;
  float q[HD], k[HD], vv[HD];
  float sq = 0.f, sk = 0.f;
#pragma unroll
  for (int d = 0; d < HD; ++d) {
    q[d] = base[(size_t)d * NPIX];
    k[d] = base[(size_t)(CC + d) * NPIX];
    vv[d] = base[(size_t)(2 * CC + d) * NPIX];
    sq += q[d] * q[d];
    sk += k[d] * k[d];
  }
  float rq = 1.f / fmaxf(sqrtf(sq), 1e-12f);
  float rk = 1.f / fmaxf(sqrtf(sk), 1e-12f);
#pragma unroll
  for (int g = 0; g < 2; ++g) {
    U4H pq, pk;
#pragma unroll
    for (int d = 0; d < 4; ++d) {
      int e = g * 8 + 2 * d;
      pq.h[d] = pkrtz(q[e] * rq, q[e + 1] * rq);
      pk.h[d] = pkrtz(k[e] * rk, k[e + 1] * rk);
    }
    qh[(size_t)idx * 2 + g] = pq.u;
    kh[(size_t)idx * 2 + g] = pk.u;
  }
  // V: LDS transpose (256 n  x 16 dims -> 16 rows x 256 n)
#pragma unroll
  for (int d = 0; d < HD; ++d) {
    union { _Float16 f; uint16_t u; } cv;
    cv.f = (_Float16)vv[d];
    lds_v[d * 256 + tid] = cv.u;
  }
  __syncthreads();
  int bh = idx >> 10;                      // block-uniform
  int n0 = (blockIdx.x * 256) & 1023;      // block-uniform
  const uint32_t* ldw = (const uint32_t*)lds_v;
  uint32_t* vtw = (uint32_t*)(vt + (size_t)bh * 16384 + n0);
#pragma unroll
  for (int r = 0; r < 8; ++r) {
    int d = 2 * r + (tid >> 7);
    int c = tid & 127;
    vtw[(size_t)d * 512 + c] = ldw[d * 128 + c];
  }
}

// ---------------- K3: sparse top-k attention via MFMA ----------------
// 1 wave = 16 q-rows. Phase 1 computes S^T = K.Q^T per 16-k-row block with
// v_mfma_f32_16x16x16f16: lane l holds scores for q = q0+(l&15), k-rows
// 16j+4*(l>>4)+e. Bisect + softmax are then fully per-lane (reduce = 2 shfls
// across the 4 lanes sharing l&15). The packed-fp16 P registers are exactly
// the B-fragment of phase 2 (O^T = V^T . P) -> zero cross-lane shuffles.
__global__ __launch_bounds__(256) void k_attn(const uint16_t* __restrict__ qh,
                                              const uint16_t* __restrict__ kh,
                                              const uint16_t* __restrict__ vt,
                                              float* __restrict__ attn_out) {
  int tid = threadIdx.x;
  int lane = tid & 63;
  int wave = tid >> 6;
  int blk = blockIdx.x;              // 1024 blocks: 16 per (b,h)
  int bh = blk >> 4;
  int q0 = ((blk & 15) << 6) | (wave << 4);
  int lm = lane & 15;
  int lg = lane >> 4;
  int b = bh >> 3, h = bh & 7;

  // B-frag: B[k=hd][n=q] = Q[q0+lm][4*lg+e], pre-scaled by 0.25 (exact fp16)
  H4U bq;
  bq.v = *(const h4f*)(qh + ((size_t)bh * 1024 + q0 + lm) * 16 + 4 * lg);
  const h2f qsc = {(_Float16)0.25f, (_Float16)0.25f};
  bq.h[0] *= qsc;
  bq.h[1] *= qsc;

  const f4 z = {0.f, 0.f, 0.f, 0.f};
  // ---- phase 1: 64 MFMAs -> 1024 scores/lane-column, packed fp16 ----
  const uint16_t* kbase = kh + (size_t)bh * 16384 + 4 * lg;
  h2f sc[64][2];
#pragma unroll
  for (int j = 0; j < 64; ++j) {
    h4f ak = *(const h4f*)(kbase + (size_t)(16 * j + lm) * 16); // A[m=krow][k=hd]
    f4 d = __builtin_amdgcn_mfma_f32_16x16x16f16(ak, bq.v, z, 0, 0, 0);
    sc[j][0] = pkrtz(d[0], d[1]);
    sc[j][1] = pkrtz(d[2], d[3]);
  }

  // ---- bisect for 512th-largest: per-lane count, 2-shfl reduce ----
  float lo = -0.26f, hi = 0.26f;
  _Float16 hlo = (_Float16)(-0.26f);
#pragma unroll 1
  for (int it = 0; it < 12; ++it) {
    float mid = 0.5f * (lo + hi);
    _Float16 hm = (_Float16)mid;
    int cc[4] = {0, 0, 0, 0};
#pragma unroll
    for (int j = 0; j < 64; ++j) {
      int a = 0;
      a += (sc[j][0][0] >= hm);
      a += (sc[j][0][1] >= hm);
      a += (sc[j][1][0] >= hm);
      a += (sc[j][1][1] >= hm);
      cc[j & 3] += a;
    }
    int c = (cc[0] + cc[1]) + (cc[2] + cc[3]);
    c += __shfl_xor(c, 16);
    c += __shfl_xor(c, 32);
    bool ge = (c >= 512);
    lo = ge ? mid : lo;
    hlo = ge ? hm : hlo;
    hi = ge ? hi : mid;
  }

  // ---- masked exp + row sum (all per-lane) ----
  float ss[2] = {0.f, 0.f};
#pragma unroll
  for (int j = 0; j < 64; ++j) {
#pragma unroll
    for (int r = 0; r < 2; ++r) {
      h2f t = sc[j][r];
      float p0 = (t[0] >= hlo) ? __expf((float)t[0]) : 0.f;
      float p1 = (t[1] >= hlo) ? __expf((float)t[1]) : 0.f;
      ss[r] += p0 + p1;
      sc[j][r] = pkrtz(p0, p1);
    }
  }
  float sum = ss[0] + ss[1];
  sum += __shfl_xor(sum, 16);
  sum += __shfl_xor(sum, 32);
  float inv = 1.f / sum;

  // ---- phase 2: O^T = V^T . P, 64 MFMAs, 4 independent acc chains ----
  const uint16_t* vbase = vt + (size_t)bh * 16384 + (size_t)lm * 1024 + 4 * lg;
  f4 acc[4] = {z, z, z, z};
#pragma unroll
  for (int j = 0; j < 64; ++j) {
    h4f va = *(const h4f*)(vbase + 16 * j);   // A[m=dim][k=krow]
    H4U pf;
    pf.h[0] = sc[j][0];
    pf.h[1] = sc[j][1];                        // B[k=krow][n=q] (direct chain)
    acc[j & 3] = __builtin_amdgcn_mfma_f32_16x16x16f16(va, pf.v, acc[j & 3], 0, 0, 0);
  }
  f4 o = (acc[0] + acc[1]) + (acc[2] + acc[3]);
#pragma unroll
  for (int e = 0; e < 4; ++e) {
    int dim = 4 * lg + e;
    attn_out[((size_t)(b * CC + h * HD + dim) * NPIX) + q0 + lm] = o[e] * inv;
  }
}

// ---------------- K5a: depthwise 3x3 SAME conv ----------------
__global__ __launch_bounds__(256) void k_dwconv(const float* __restrict__ in,
                                                const float* __restrict__ w,
                                                float* __restrict__ out) {
  int n = blockIdx.x * 256 + threadIdx.x;
  int c = blockIdx.y, b = blockIdx.z;
  int i = n >> 5, j = n & 31;
  const float* inb = in + ((size_t)b * C3 + c) * NPIX;
  const float* wc = w + c * 9;
  float acc = 0.f;
#pragma unroll
  for (int di = -1; di <= 1; ++di) {
    int ii = i + di;
    if (ii < 0 || ii > 31) continue;
#pragma unroll
    for (int dj = -1; dj <= 1; ++dj) {
      int jj = j + dj;
      if (jj < 0 || jj > 31) continue;
      acc += inb[ii * 32 + jj] * wc[(di + 1) * 3 + (dj + 1)];
    }
  }
  out[((size_t)b * C3 + c) * NPIX + n] = acc;
}

// ---------------- GroupNorm (32 groups) + fused epilogue, float4, 512 thr ----
template <int ACT, bool HAS_RES>
__global__ __launch_bounds__(512) void k_gn(const float* __restrict__ x,
                                            const float* __restrict__ res,
                                            float* __restrict__ out,
                                            const float* __restrict__ gamma,
                                            const float* __restrict__ beta,
                                            const float* __restrict__ alpha_ptr,
                                            float alpha_const,
                                            int chPerGroup, int Npix, int nshift) {
  int g = blockIdx.x & 31, b = blockIdx.x >> 5;
  int Cout = 32 * chPerGroup;
  int elems = chPerGroup * Npix;
  int nv = elems >> 2;
  size_t base = ((size_t)b * Cout + g * chPerGroup) * Npix;
  const float4* xv = (const float4*)(x + base);
  int tid = threadIdx.x;
  float s = 0.f, s2 = 0.f;
  for (int i = tid; i < nv; i += 512) {
    float4 v = xv[i];
    s += v.x + v.y + v.z + v.w;
    s2 += v.x * v.x + v.y * v.y + v.z * v.z + v.w * v.w;
  }
#pragma unroll
  for (int off = 32; off > 0; off >>= 1) {
    s += __shfl_xor(s, off);
    s2 += __shfl_xor(s2, off);
  }
  __shared__ float ls[8], ls2[8];
  int wv = tid >> 6, ln = tid & 63;
  if (ln == 0) { ls[wv] = s; ls2[wv] = s2; }
  __syncthreads();
  float st = 0.f, s2t = 0.f;
#pragma unroll
  for (int i = 0; i < 8; ++i) { st += ls[i]; s2t += ls2[i]; }
  float inv_n = 1.f / (float)elems;
  float mean = st * inv_n;
  float var = s2t * inv_n - mean * mean;
  float rstd = rsqrtf(var + 1e-6f);
  float a = alpha_ptr ? alpha_ptr[0] : alpha_const;
  const float4* rv = (const float4*)(res + base);
  float4* ov = (float4*)(out + base);
  int cshift = nshift - 2;
  for (int i = tid; i < nv; i += 512) {
    float4 v = xv[i];
    int cc = g * chPerGroup + (i >> cshift);
    float gm = gamma[cc], bt = beta[cc];
    float r[4] = {v.x, v.y, v.z, v.w};
#pragma unroll
    for (int p = 0; p < 4; ++p) {
      float gnv = (r[p] - mean) * rstd * gm + bt;
      if (ACT == 1)      r[p] = gnv / (1.f + __expf(-gnv));
      else if (ACT == 2) r[p] = 0.5f * gnv * (1.f + erff(gnv * 0.70710678118654752f));
      else               r[p] = gnv;
    }
    float4 o;
    if (HAS_RES) {
      float4 rr = rv[i];
      o = make_float4(rr.x + a * r[0], rr.y + a * r[1], rr.z + a * r[2], rr.w + a * r[3]);
    } else {
      o = make_float4(r[0], r[1], r[2], r[3]);
    }
    ov[i] = o;
  }
}

// ---------------- K6: IWT + residual ----------------
__global__ __launch_bounds__(256) void k_iwt(const float* __restrict__ x,
                                             const float* __restrict__ s1,
                                             const float* __restrict__ hout,
                                             float* __restrict__ out) {
  int idx = blockIdx.x * 256 + threadIdx.x;  // B*C*32*32
  int w = idx & 31, h = (idx >> 5) & 31, c = (idx >> 10) & 127, b = idx >> 17;
  int n = h * 32 + w;
  float ll = s1[(size_t)(b * CC + c) * NPIX + n];
  float lh = hout[((size_t)b * C3 + c) * NPIX + n];
  float hl = hout[((size_t)b * C3 + CC + c) * NPIX + n];
  float hh = hout[((size_t)b * C3 + 2 * CC + c) * NPIX + n];
  float va = ll - lh - hl + hh;
  float vb = ll - lh + hl - hh;
  float vc = ll + lh - hl - hh;
  float vd = ll + lh + hl + hh;
  size_t xb = ((size_t)(b * CC + c) * HH + 2 * h) * HH + 2 * w;
  out[xb]          = x[xb]          + 0.1f * va;
  out[xb + 1]      = x[xb + 1]      + 0.1f * vc;
  out[xb + HH]     = x[xb + HH]     + 0.1f * vb;
  out[xb + HH + 1] = x[xb + HH + 1] + 0.1f * vd;
}

extern "C" void kernel_launch(void* const* d_in, const int* in_sizes, int n_in,
                              void* d_out, int out_size, void* d_ws, size_t ws_size,
                              hipStream_t stream) {
  const float* x         = (const float*)d_in[0];
  const float* qkv_w     = (const float*)d_in[1];
  const float* proj_w    = (const float*)d_in[2];
  const float* attn_gn_g = (const float*)d_in[3];
  const float* attn_gn_b = (const float*)d_in[4];
  const float* he_dw_w   = (const float*)d_in[5];
  const float* he_gn1_g  = (const float*)d_in[6];
  const float* he_gn1_b  = (const float*)d_in[7];
  const float* he_pw_w   = (const float*)d_in[8];
  const float* he_gn2_g  = (const float*)d_in[9];
  const float* he_gn2_b  = (const float*)d_in[10];
  const float* alpha     = (const float*)d_in[11];
  const float* ffn_w1    = (const float*)d_in[12];
  const float* ffn_gn1_g = (const float*)d_in[13];
  const float* ffn_gn1_b = (const float*)d_in[14];
  const float* ffn_w2    = (const float*)d_in[15];
  const float* ffn_gn2_g = (const float*)d_in[16];
  const float* ffn_gn2_b = (const float*)d_in[17];
  float* out = (float*)d_out;

  float* ws = (float*)d_ws;
  float* ll   = ws;              // 1,048,576
  float* high = ws + 1048576;    // 3,145,728
  float* qkv  = ws + 4194304;    // 3,145,728 ; reused as y1
  float* qnkv = ws + 7340032;    // 3,145,728 ; qh|kh|vt (fp16) ; reused as pw/h_out
  float* atto = ws + 10485760;   // 1,048,576
  float* proj = ws + 11534336;   // 1,048,576
  float* f1   = ws + 12582912;   // 8,388,608
  float* f3   = ws + 20971520;   // 4,194,304
  uint4* qh = (uint4*)qnkv;
  uint4* kh = (uint4*)(qnkv + 524288);
  uint16_t* vt = (uint16_t*)(qnkv + 1048576);   // [bh][16][1024] fp16
  float* y1 = qkv;
  float* pw = qnkv;

  // 1) DWT
  k_dwt<<<4096, 256, 0, stream>>>(x, ll, high);
  // 2) qkv = conv1x1(ll, qkv_w); split + l2norm -> packed fp16 (+ V^T)
  k_conv1x1<128, 1, 8><<<dim3(4, 48, 8), 256, 0, stream>>>(ll, qkv_w, qkv, 384, 1024);
  k_qkvnorm<<<256, 256, 0, stream>>>(qkv, qh, kh, vt);
  // 3) sparse attention (MFMA, 16 q-rows per wave)
  k_attn<<<1024, 256, 0, stream>>>((const uint16_t*)qh, (const uint16_t*)kh, vt, atto);
  // 4) proj + groupnorm, s1 = ll + gn(proj)
  k_conv1x1<128, 1, 4><<<dim3(4, 32, 8), 256, 0, stream>>>(atto, proj_w, proj, 128, 1024);
  k_gn<0, true><<<256, 512, 0, stream>>>(proj, ll, proj, attn_gn_g, attn_gn_b,
                                         nullptr, 1.0f, 4, 1024, 10);
  // 5) high enhance
  k_dwconv<<<dim3(4, 384, 8), 256, 0, stream>>>(high, he_dw_w, y1);
  k_gn<1, false><<<256, 512, 0, stream>>>(y1, nullptr, y1, he_gn1_g, he_gn1_b,
                                          nullptr, 0.f, 12, 1024, 10);
  k_conv1x1<384, 1, 8><<<dim3(4, 48, 8), 256, 0, stream>>>(y1, he_pw_w, pw, 384, 1024);
  k_gn<0, true><<<256, 512, 0, stream>>>(pw, high, pw, he_gn2_g, he_gn2_b,
                                         alpha, 0.f, 12, 1024, 10);
  // 6) IWT + residual -> out
  k_iwt<<<4096, 256, 0, stream>>>(x, proj, pw, out);
  // 7) FFN
  k_conv1x1<128, 2, 8><<<dim3(8, 32, 8), 256, 0, stream>>>(out, ffn_w1, f1, 256, 4096);
  k_gn<2, false><<<256, 512, 0, stream>>>(f1, nullptr, f1, ffn_gn1_g, ffn_gn1_b,
                                          nullptr, 0.f, 8, 4096, 12);
  k_conv1x1<256, 2, 8><<<dim3(8, 16, 8), 256, 0, stream>>>(f1, ffn_w2, f3, 128, 4096);
  k_gn<0, true><<<256, 512, 0, stream>>>(f3, out, out, ffn_gn2_g, ffn_gn2_b,
                                         nullptr, 0.1f, 4, 4096, 12);
  (void)in_sizes; (void)n_in; (void)out_size; (void)ws_size;
}

// Round 5
// 398.544 us; speedup vs baseline: 1.9322x; 1.0453x over previous
//
#include <hip/hip_runtime.h>
#include <cstdint>
#include <cstddef>

// Dims (fixed by the problem)
#define BB 8
#define CC 128
#define C3 384
#define HH 64
#define H2 32
#define NPIX 1024   // 32*32
#define N4 4096     // 64*64
#define NHD 8
#define HD 16

typedef _Float16 h2f __attribute__((ext_vector_type(2)));
typedef _Float16 h4f __attribute__((ext_vector_type(4)));
typedef float f4 __attribute__((ext_vector_type(4)));

union U4H { uint4 u; h2f h[4]; };
union H4U { h4f v; h2f h[2]; };

__device__ inline h2f pkrtz(float a, float b) {
  return __builtin_bit_cast(h2f, __builtin_amdgcn_cvt_pkrtz(a, b));
}

// ---------------- K1: Haar DWT ----------------
__global__ __launch_bounds__(256) void k_dwt(const float* __restrict__ x,
                                             float* __restrict__ ll,
                                             float* __restrict__ high) {
  int idx = blockIdx.x * 256 + threadIdx.x;   // B*C*32*32 = 1,048,576
  int w = idx & 31, h = (idx >> 5) & 31, c = (idx >> 10) & 127, b = idx >> 17;
  const float* xp = x + ((size_t)(b * CC + c) * HH + 2 * h) * HH + 2 * w;
  float x1 = xp[0];
  float x2 = xp[HH];
  float x3 = xp[1];
  float x4 = xp[HH + 1];
  int n = h * H2 + w;
  ll[(size_t)(b * CC + c) * NPIX + n]              = 0.5f * ( x1 + x2 + x3 + x4);
  high[((size_t)b * C3 + c) * NPIX + n]            = 0.5f * (-x1 - x2 + x3 + x4);
  high[((size_t)b * C3 + CC + c) * NPIX + n]       = 0.5f * (-x1 + x2 - x3 + x4);
  high[((size_t)b * C3 + 2 * CC + c) * NPIX + n]   = 0.5f * ( x1 - x2 - x3 + x4);
}

// ---------------- conv1x1: register GEMV; OPT outs x P pixels per thread ----
template <int CIN, int P, int OPT>
__global__ __launch_bounds__(256) void k_conv1x1(const float* __restrict__ in,
                                                 const float* __restrict__ w,
                                                 float* __restrict__ out,
                                                 int Cout, int Npix) {
  int tid = threadIdx.x;
  int n0 = (blockIdx.x * 256 + tid) * P;
  int o0 = blockIdx.y * OPT;
  int b = blockIdx.z;
  const float* inb = in + (size_t)b * CIN * Npix + n0;
  const float* wb = w + (size_t)o0 * CIN;
  float acc[OPT][P];
#pragma unroll
  for (int o = 0; o < OPT; ++o)
#pragma unroll
    for (int p = 0; p < P; ++p) acc[o][p] = 0.f;

  for (int c0 = 0; c0 < CIN; c0 += 8) {
#pragma unroll
    for (int c = 0; c < 8; ++c) {
      float vv[P];
      const float* ip = inb + (size_t)(c0 + c) * Npix;
      if constexpr (P == 4) {
        float4 t = *(const float4*)ip;
        vv[0] = t.x; vv[1] = t.y; vv[2] = t.z; vv[3] = t.w;
      } else if constexpr (P == 2) {
        float2 t = *(const float2*)ip;
        vv[0] = t.x; vv[1] = t.y;
      } else {
        vv[0] = ip[0];
      }
#pragma unroll
      for (int o = 0; o < OPT; ++o) {
        float wc = wb[(size_t)o * CIN + c0 + c];   // uniform -> s_load
#pragma unroll
        for (int p = 0; p < P; ++p) acc[o][p] = fmaf(wc, vv[p], acc[o][p]);
      }
    }
  }
  size_t ob = ((size_t)b * Cout + o0) * Npix + n0;
#pragma unroll
  for (int o = 0; o < OPT; ++o) {
    float* op = out + ob + (size_t)o * Npix;
    if constexpr (P == 4) {
      *(float4*)op = make_float4(acc[o][0], acc[o][1], acc[o][2], acc[o][3]);
    } else if constexpr (P == 2) {
      *(float2*)op = make_float2(acc[o][0], acc[o][1]);
    } else {
      op[0] = acc[o][0];
    }
  }
}

// ---------------- K2b: split qkv + l2norm q,k -> fp16; V -> transposed vt ----
// vt layout: [bh][dim(16)][1024] fp16 (A-fragment-friendly for phase 2 MFMA)
__global__ __launch_bounds__(256) void k_qkvnorm(const float* __restrict__ qkv,
                                                 uint4* __restrict__ qh,
                                                 uint4* __restrict__ kh,
                                                 uint16_t* __restrict__ vt) {
  __shared__ uint16_t lds_v[16 * 256];
  int tid = threadIdx.x;
  int idx = blockIdx.x * 256 + tid;  // 65536 = B*NH*NPIX
  int n = idx & 1023, h = (idx >> 10) & 7, b = idx >> 13;
  const float* base = qkv + ((size_t)b * C3 + h * HD) * NPIX + n;
  float q[HD], k[HD], vv[HD];
  float sq = 0.f, sk = 0.f;
#pragma unroll
  for (int d = 0; d < HD; ++d) {
    q[d] = base[(size_t)d * NPIX];
    k[d] = base[(size_t)(CC + d) * NPIX];
    vv[d] = base[(size_t)(2 * CC + d) * NPIX];
    sq += q[d] * q[d];
    sk += k[d] * k[d];
  }
  float rq = 1.f / fmaxf(sqrtf(sq), 1e-12f);
  float rk = 1.f / fmaxf(sqrtf(sk), 1e-12f);
#pragma unroll
  for (int g = 0; g < 2; ++g) {
    U4H pq, pk;
#pragma unroll
    for (int d = 0; d < 4; ++d) {
      int e = g * 8 + 2 * d;
      pq.h[d] = pkrtz(q[e] * rq, q[e + 1] * rq);
      pk.h[d] = pkrtz(k[e] * rk, k[e + 1] * rk);
    }
    qh[(size_t)idx * 2 + g] = pq.u;
    kh[(size_t)idx * 2 + g] = pk.u;
  }
  // V: LDS transpose (256 n  x 16 dims -> 16 rows x 256 n)
#pragma unroll
  for (int d = 0; d < HD; ++d) {
    union { _Float16 f; uint16_t u; } cv;
    cv.f = (_Float16)vv[d];
    lds_v[d * 256 + tid] = cv.u;
  }
  __syncthreads();
  int bh = idx >> 10;                      // block-uniform
  int n0 = (blockIdx.x * 256) & 1023;      // block-uniform
  const uint32_t* ldw = (const uint32_t*)lds_v;
  uint32_t* vtw = (uint32_t*)(vt + (size_t)bh * 16384 + n0);
#pragma unroll
  for (int r = 0; r < 8; ++r) {
    int d = 2 * r + (tid >> 7);
    int c = tid & 127;
    vtw[(size_t)d * 512 + c] = ldw[d * 128 + c];
  }
}

// ---------------- K3: sparse top-k attention via MFMA, 4-wave split-K ----
// Block = 16 q-rows; wave w handles k-rows [w*256, w*256+256). Per-lane score
// state = 32 u32 (no AGPR overflow). Bisect counts / softmax sum combined
// across waves via per-iteration LDS slots (1 barrier each). Phase-2 partial
// O (fp32) reduced through LDS at the end. Indexing identical to the verified
// round-4 kernel with J = w*16 + j.
__global__ __launch_bounds__(256) void k_attn(const uint16_t* __restrict__ qh,
                                              const uint16_t* __restrict__ kh,
                                              const uint16_t* __restrict__ vt,
                                              float* __restrict__ attn_out) {
  __shared__ int cnt_lds[12 * 64];     // [it][lm][w]
  __shared__ float sum_lds[64];        // [lm][w]
  __shared__ f4 obuf[4 * 64];          // [w][lane]
  int tid = threadIdx.x;
  int lane = tid & 63;
  int w = tid >> 6;
  int blk = blockIdx.x;                // 4096 blocks: 64 per (b,h)
  int bh = blk >> 6;
  int q0 = (blk & 63) << 4;
  int lm = lane & 15;
  int lg = lane >> 4;
  int b = bh >> 3, h = bh & 7;

  // B-frag: B[k=hd][n=q] = Q[q0+lm][4*lg+e], pre-scaled by 0.25 (exact fp16)
  H4U bq;
  bq.v = *(const h4f*)(qh + ((size_t)bh * 1024 + q0 + lm) * 16 + 4 * lg);
  const h2f qsc = {(_Float16)0.25f, (_Float16)0.25f};
  bq.h[0] *= qsc;
  bq.h[1] *= qsc;

  const f4 z = {0.f, 0.f, 0.f, 0.f};
  // ---- phase 1: 16 MFMAs/wave -> 64 scores/lane, packed fp16 ----
  const uint16_t* kbase = kh + (size_t)bh * 16384 + 4 * lg;
  h2f sc[16][2];
#pragma unroll
  for (int j = 0; j < 16; ++j) {
    int J = (w << 4) | j;
    h4f ak = *(const h4f*)(kbase + (size_t)(16 * J + lm) * 16); // A[m=krow][k=hd]
    f4 d = __builtin_amdgcn_mfma_f32_16x16x16f16(ak, bq.v, z, 0, 0, 0);
    sc[j][0] = pkrtz(d[0], d[1]);
    sc[j][1] = pkrtz(d[2], d[3]);
  }

  // ---- bisect for 512th-largest: per-lane count, shfl + LDS cross-wave ----
  float lo = -0.26f, hi = 0.26f;
  _Float16 hlo = (_Float16)(-0.26f);
#pragma unroll 1
  for (int it = 0; it < 12; ++it) {
    float mid = 0.5f * (lo + hi);
    _Float16 hm = (_Float16)mid;
    int c = 0;
#pragma unroll
    for (int j = 0; j < 16; ++j) {
      c += (sc[j][0][0] >= hm);
      c += (sc[j][0][1] >= hm);
      c += (sc[j][1][0] >= hm);
      c += (sc[j][1][1] >= hm);
    }
    c += __shfl_xor(c, 16);
    c += __shfl_xor(c, 32);
    if (lg == 0) cnt_lds[it * 64 + lm * 4 + w] = c;
    __syncthreads();
    int4 c4 = *(const int4*)&cnt_lds[it * 64 + lm * 4];
    int ct = (c4.x + c4.y) + (c4.z + c4.w);
    bool ge = (ct >= 512);
    lo = ge ? mid : lo;
    hlo = ge ? hm : hlo;
    hi = ge ? hi : mid;
  }

  // ---- masked exp + row sum ----
  float ss = 0.f;
#pragma unroll
  for (int j = 0; j < 16; ++j) {
#pragma unroll
    for (int r = 0; r < 2; ++r) {
      h2f t = sc[j][r];
      float p0 = (t[0] >= hlo) ? __expf((float)t[0]) : 0.f;
      float p1 = (t[1] >= hlo) ? __expf((float)t[1]) : 0.f;
      ss += p0 + p1;
      sc[j][r] = pkrtz(p0, p1);
    }
  }
  ss += __shfl_xor(ss, 16);
  ss += __shfl_xor(ss, 32);
  if (lg == 0) sum_lds[lm * 4 + w] = ss;
  __syncthreads();
  float4 s4 = *(const float4*)&sum_lds[lm * 4];
  float inv = 1.f / ((s4.x + s4.y) + (s4.z + s4.w));

  // ---- phase 2: O^T = V^T . P over this wave's k-rows, fp32 accum ----
  const uint16_t* vbase = vt + (size_t)bh * 16384 + (size_t)lm * 1024 + 4 * lg;
  f4 acc[2] = {z, z};
#pragma unroll
  for (int j = 0; j < 16; ++j) {
    int J = (w << 4) | j;
    h4f va = *(const h4f*)(vbase + 16 * J);   // A[m=dim][k=krow]
    H4U pf;
    pf.h[0] = sc[j][0];
    pf.h[1] = sc[j][1];                        // B[k=krow][n=q]
    acc[j & 1] = __builtin_amdgcn_mfma_f32_16x16x16f16(va, pf.v, acc[j & 1], 0, 0, 0);
  }
  f4 o = acc[0] + acc[1];
  obuf[(w << 6) | lane] = o;
  __syncthreads();
  if (w == 0) {
    f4 t = obuf[lane] + obuf[64 + lane] + obuf[128 + lane] + obuf[192 + lane];
#pragma unroll
    for (int e = 0; e < 4; ++e) {
      int dim = 4 * lg + e;
      attn_out[((size_t)(b * CC + h * HD + dim) * NPIX) + q0 + lm] = t[e] * inv;
    }
  }
}

// ---------------- K5a: depthwise 3x3 SAME conv ----------------
__global__ __launch_bounds__(256) void k_dwconv(const float* __restrict__ in,
                                                const float* __restrict__ w,
                                                float* __restrict__ out) {
  int n = blockIdx.x * 256 + threadIdx.x;
  int c = blockIdx.y, b = blockIdx.z;
  int i = n >> 5, j = n & 31;
  const float* inb = in + ((size_t)b * C3 + c) * NPIX;
  const float* wc = w + c * 9;
  float acc = 0.f;
#pragma unroll
  for (int di = -1; di <= 1; ++di) {
    int ii = i + di;
    if (ii < 0 || ii > 31) continue;
#pragma unroll
    for (int dj = -1; dj <= 1; ++dj) {
      int jj = j + dj;
      if (jj < 0 || jj > 31) continue;
      acc += inb[ii * 32 + jj] * wc[(di + 1) * 3 + (dj + 1)];
    }
  }
  out[((size_t)b * C3 + c) * NPIX + n] = acc;
}

// ---------------- GroupNorm (32 groups) + fused epilogue, float4, 512 thr ----
template <int ACT, bool HAS_RES>
__global__ __launch_bounds__(512) void k_gn(const float* __restrict__ x,
                                            const float* __restrict__ res,
                                            float* __restrict__ out,
                                            const float* __restrict__ gamma,
                                            const float* __restrict__ beta,
                                            const float* __restrict__ alpha_ptr,
                                            float alpha_const,
                                            int chPerGroup, int Npix, int nshift) {
  int g = blockIdx.x & 31, b = blockIdx.x >> 5;
  int Cout = 32 * chPerGroup;
  int elems = chPerGroup * Npix;
  int nv = elems >> 2;
  size_t base = ((size_t)b * Cout + g * chPerGroup) * Npix;
  const float4* xv = (const float4*)(x + base);
  int tid = threadIdx.x;
  float s = 0.f, s2 = 0.f;
  for (int i = tid; i < nv; i += 512) {
    float4 v = xv[i];
    s += v.x + v.y + v.z + v.w;
    s2 += v.x * v.x + v.y * v.y + v.z * v.z + v.w * v.w;
  }
#pragma unroll
  for (int off = 32; off > 0; off >>= 1) {
    s += __shfl_xor(s, off);
    s2 += __shfl_xor(s2, off);
  }
  __shared__ float ls[8], ls2[8];
  int wv = tid >> 6, ln = tid & 63;
  if (ln == 0) { ls[wv] = s; ls2[wv] = s2; }
  __syncthreads();
  float st = 0.f, s2t = 0.f;
#pragma unroll
  for (int i = 0; i < 8; ++i) { st += ls[i]; s2t += ls2[i]; }
  float inv_n = 1.f / (float)elems;
  float mean = st * inv_n;
  float var = s2t * inv_n - mean * mean;
  float rstd = rsqrtf(var + 1e-6f);
  float a = alpha_ptr ? alpha_ptr[0] : alpha_const;
  const float4* rv = (const float4*)(res + base);
  float4* ov = (float4*)(out + base);
  int cshift = nshift - 2;
  for (int i = tid; i < nv; i += 512) {
    float4 v = xv[i];
    int cc = g * chPerGroup + (i >> cshift);
    float gm = gamma[cc], bt = beta[cc];
    float r[4] = {v.x, v.y, v.z, v.w};
#pragma unroll
    for (int p = 0; p < 4; ++p) {
      float gnv = (r[p] - mean) * rstd * gm + bt;
      if (ACT == 1)      r[p] = gnv / (1.f + __expf(-gnv));
      else if (ACT == 2) r[p] = 0.5f * gnv * (1.f + erff(gnv * 0.70710678118654752f));
      else               r[p] = gnv;
    }
    float4 o;
    if (HAS_RES) {
      float4 rr = rv[i];
      o = make_float4(rr.x + a * r[0], rr.y + a * r[1], rr.z + a * r[2], rr.w + a * r[3]);
    } else {
      o = make_float4(r[0], r[1], r[2], r[3]);
    }
    ov[i] = o;
  }
}

// ---------------- K6: IWT + residual ----------------
__global__ __launch_bounds__(256) void k_iwt(const float* __restrict__ x,
                                             const float* __restrict__ s1,
                                             const float* __restrict__ hout,
                                             float* __restrict__ out) {
  int idx = blockIdx.x * 256 + threadIdx.x;  // B*C*32*32
  int w = idx & 31, h = (idx >> 5) & 31, c = (idx >> 10) & 127, b = idx >> 17;
  int n = h * 32 + w;
  float ll = s1[(size_t)(b * CC + c) * NPIX + n];
  float lh = hout[((size_t)b * C3 + c) * NPIX + n];
  float hl = hout[((size_t)b * C3 + CC + c) * NPIX + n];
  float hh = hout[((size_t)b * C3 + 2 * CC + c) * NPIX + n];
  float va = ll - lh - hl + hh;
  float vb = ll - lh + hl - hh;
  float vc = ll + lh - hl - hh;
  float vd = ll + lh + hl + hh;
  size_t xb = ((size_t)(b * CC + c) * HH + 2 * h) * HH + 2 * w;
  out[xb]          = x[xb]          + 0.1f * va;
  out[xb + 1]      = x[xb + 1]      + 0.1f * vc;
  out[xb + HH]     = x[xb + HH]     + 0.1f * vb;
  out[xb + HH + 1] = x[xb + HH + 1] + 0.1f * vd;
}

extern "C" void kernel_launch(void* const* d_in, const int* in_sizes, int n_in,
                              void* d_out, int out_size, void* d_ws, size_t ws_size,
                              hipStream_t stream) {
  const float* x         = (const float*)d_in[0];
  const float* qkv_w     = (const float*)d_in[1];
  const float* proj_w    = (const float*)d_in[2];
  const float* attn_gn_g = (const float*)d_in[3];
  const float* attn_gn_b = (const float*)d_in[4];
  const float* he_dw_w   = (const float*)d_in[5];
  const float* he_gn1_g  = (const float*)d_in[6];
  const float* he_gn1_b  = (const float*)d_in[7];
  const float* he_pw_w   = (const float*)d_in[8];
  const float* he_gn2_g  = (const float*)d_in[9];
  const float* he_gn2_b  = (const float*)d_in[10];
  const float* alpha     = (const float*)d_in[11];
  const float* ffn_w1    = (const float*)d_in[12];
  const float* ffn_gn1_g = (const float*)d_in[13];
  const float* ffn_gn1_b = (const float*)d_in[14];
  const float* ffn_w2    = (const float*)d_in[15];
  const float* ffn_gn2_g = (const float*)d_in[16];
  const float* ffn_gn2_b = (const float*)d_in[17];
  float* out = (float*)d_out;

  float* ws = (float*)d_ws;
  float* ll   = ws;              // 1,048,576
  float* high = ws + 1048576;    // 3,145,728
  float* qkv  = ws + 4194304;    // 3,145,728 ; reused as y1
  float* qnkv = ws + 7340032;    // 3,145,728 ; qh|kh|vt (fp16) ; reused as pw/h_out
  float* atto = ws + 10485760;   // 1,048,576
  float* proj = ws + 11534336;   // 1,048,576
  float* f1   = ws + 12582912;   // 8,388,608
  float* f3   = ws + 20971520;   // 4,194,304
  uint4* qh = (uint4*)qnkv;
  uint4* kh = (uint4*)(qnkv + 524288);
  uint16_t* vt = (uint16_t*)(qnkv + 1048576);   // [bh][16][1024] fp16
  float* y1 = qkv;
  float* pw = qnkv;

  // 1) DWT
  k_dwt<<<4096, 256, 0, stream>>>(x, ll, high);
  // 2) qkv = conv1x1(ll, qkv_w); split + l2norm -> packed fp16 (+ V^T)
  k_conv1x1<128, 1, 8><<<dim3(4, 48, 8), 256, 0, stream>>>(ll, qkv_w, qkv, 384, 1024);
  k_qkvnorm<<<256, 256, 0, stream>>>(qkv, qh, kh, vt);
  // 3) sparse attention (MFMA, 4-wave split-K, 16 q-rows per block)
  k_attn<<<4096, 256, 0, stream>>>((const uint16_t*)qh, (const uint16_t*)kh, vt, atto);
  // 4) proj + groupnorm, s1 = ll + gn(proj)
  k_conv1x1<128, 1, 4><<<dim3(4, 32, 8), 256, 0, stream>>>(atto, proj_w, proj, 128, 1024);
  k_gn<0, true><<<256, 512, 0, stream>>>(proj, ll, proj, attn_gn_g, attn_gn_b,
                                         nullptr, 1.0f, 4, 1024, 10);
  // 5) high enhance
  k_dwconv<<<dim3(4, 384, 8), 256, 0, stream>>>(high, he_dw_w, y1);
  k_gn<1, false><<<256, 512, 0, stream>>>(y1, nullptr, y1, he_gn1_g, he_gn1_b,
                                          nullptr, 0.f, 12, 1024, 10);
  k_conv1x1<384, 1, 8><<<dim3(4, 48, 8), 256, 0, stream>>>(y1, he_pw_w, pw, 384, 1024);
  k_gn<0, true><<<256, 512, 0, stream>>>(pw, high, pw, he_gn2_g, he_gn2_b,
                                         alpha, 0.f, 12, 1024, 10);
  // 6) IWT + residual -> out
  k_iwt<<<4096, 256, 0, stream>>>(x, proj, pw, out);
  // 7) FFN
  k_conv1x1<128, 2, 8><<<dim3(8, 32, 8), 256, 0, stream>>>(out, ffn_w1, f1, 256, 4096);
  k_gn<2, false><<<256, 512, 0, stream>>>(f1, nullptr, f1, ffn_gn1_g, ffn_gn1_b,
                                          nullptr, 0.f, 8, 4096, 12);
  k_conv1x1<256, 2, 8><<<dim3(8, 16, 8), 256, 0, stream>>>(f1, ffn_w2, f3, 128, 4096);
  k_gn<0, true><<<256, 512, 0, stream>>>(f3, out, out, ffn_gn2_g, ffn_gn2_b,
                                         nullptr, 0.1f, 4, 4096, 12);
  (void)in_sizes; (void)n_in; (void)out_size; (void)ws_size;
}

// Round 6
// 383.115 us; speedup vs baseline: 2.0100x; 1.0403x over previous
//
#include <hip/hip_runtime.h>
#include <cstdint>
#include <cstddef>

// Dims (fixed by the problem)
#define BB 8
#define CC 128
#define C3 384
#define HH 64
#define H2 32
#define NPIX 1024   // 32*32
#define N4 4096     // 64*64
#define NHD 8
#define HD 16

typedef _Float16 h2f __attribute__((ext_vector_type(2)));
typedef _Float16 h4f __attribute__((ext_vector_type(4)));
typedef float f4 __attribute__((ext_vector_type(4)));

union U4H { uint4 u; h2f h[4]; };
union H4U { h4f v; h2f h[2]; };

__device__ inline h2f pkrtz(float a, float b) {
  return __builtin_bit_cast(h2f, __builtin_amdgcn_cvt_pkrtz(a, b));
}

// ---------------- K1: Haar DWT ----------------
__global__ __launch_bounds__(256) void k_dwt(const float* __restrict__ x,
                                             float* __restrict__ ll,
                                             float* __restrict__ high) {
  int idx = blockIdx.x * 256 + threadIdx.x;   // B*C*32*32 = 1,048,576
  int w = idx & 31, h = (idx >> 5) & 31, c = (idx >> 10) & 127, b = idx >> 17;
  const float* xp = x + ((size_t)(b * CC + c) * HH + 2 * h) * HH + 2 * w;
  float x1 = xp[0];
  float x2 = xp[HH];
  float x3 = xp[1];
  float x4 = xp[HH + 1];
  int n = h * H2 + w;
  ll[(size_t)(b * CC + c) * NPIX + n]              = 0.5f * ( x1 + x2 + x3 + x4);
  high[((size_t)b * C3 + c) * NPIX + n]            = 0.5f * (-x1 - x2 + x3 + x4);
  high[((size_t)b * C3 + CC + c) * NPIX + n]       = 0.5f * (-x1 + x2 - x3 + x4);
  high[((size_t)b * C3 + 2 * CC + c) * NPIX + n]   = 0.5f * ( x1 - x2 - x3 + x4);
}

// ---------------- conv1x1: register GEMV; OPT outs x P pixels per thread ----
// SWZ: 1-D grid, decode (b,x,y) so same-(b,x) blocks share an XCD (L%8 const).
template <int CIN, int P, int OPT, bool SWZ = false>
__global__ __launch_bounds__(256) void k_conv1x1(const float* __restrict__ in,
                                                 const float* __restrict__ w,
                                                 float* __restrict__ out,
                                                 int Cout, int Npix) {
  int tid = threadIdx.x;
  int n0, o0, b;
  if constexpr (SWZ) {
    int L = blockIdx.x;          // (b*4 + x) + 32*y ; L%8 invariant over y
    int low = L & 31;
    b = low >> 2;
    n0 = ((low & 3) * 256 + tid) * P;
    o0 = (L >> 5) * OPT;
  } else {
    n0 = (blockIdx.x * 256 + tid) * P;
    o0 = blockIdx.y * OPT;
    b = blockIdx.z;
  }
  const float* inb = in + (size_t)b * CIN * Npix + n0;
  const float* wb = w + (size_t)o0 * CIN;
  float acc[OPT][P];
#pragma unroll
  for (int o = 0; o < OPT; ++o)
#pragma unroll
    for (int p = 0; p < P; ++p) acc[o][p] = 0.f;

  for (int c0 = 0; c0 < CIN; c0 += 8) {
#pragma unroll
    for (int c = 0; c < 8; ++c) {
      float vv[P];
      const float* ip = inb + (size_t)(c0 + c) * Npix;
      if constexpr (P == 4) {
        float4 t = *(const float4*)ip;
        vv[0] = t.x; vv[1] = t.y; vv[2] = t.z; vv[3] = t.w;
      } else if constexpr (P == 2) {
        float2 t = *(const float2*)ip;
        vv[0] = t.x; vv[1] = t.y;
      } else {
        vv[0] = ip[0];
      }
#pragma unroll
      for (int o = 0; o < OPT; ++o) {
        float wc = wb[(size_t)o * CIN + c0 + c];   // uniform -> s_load
#pragma unroll
        for (int p = 0; p < P; ++p) acc[o][p] = fmaf(wc, vv[p], acc[o][p]);
      }
    }
  }
  size_t ob = ((size_t)b * Cout + o0) * Npix + n0;
#pragma unroll
  for (int o = 0; o < OPT; ++o) {
    float* op = out + ob + (size_t)o * Npix;
    if constexpr (P == 4) {
      *(float4*)op = make_float4(acc[o][0], acc[o][1], acc[o][2], acc[o][3]);
    } else if constexpr (P == 2) {
      *(float2*)op = make_float2(acc[o][0], acc[o][1]);
    } else {
      op[0] = acc[o][0];
    }
  }
}

// ---------------- K2b: split qkv + l2norm q,k -> fp16; V -> transposed vt ----
__global__ __launch_bounds__(256) void k_qkvnorm(const float* __restrict__ qkv,
                                                 uint4* __restrict__ qh,
                                                 uint4* __restrict__ kh,
                                                 uint16_t* __restrict__ vt) {
  __shared__ uint16_t lds_v[16 * 256];
  int tid = threadIdx.x;
  int idx = blockIdx.x * 256 + tid;  // 65536 = B*NH*NPIX
  int n = idx & 1023, h = (idx >> 10) & 7, b = idx >> 13;
  const float* base = qkv + ((size_t)b * C3 + h * HD) * NPIX + n;
  float q[HD], k[HD], vv[HD];
  float sq = 0.f, sk = 0.f;
#pragma unroll
  for (int d = 0; d < HD; ++d) {
    q[d] = base[(size_t)d * NPIX];
    k[d] = base[(size_t)(CC + d) * NPIX];
    vv[d] = base[(size_t)(2 * CC + d) * NPIX];
    sq += q[d] * q[d];
    sk += k[d] * k[d];
  }
  float rq = 1.f / fmaxf(sqrtf(sq), 1e-12f);
  float rk = 1.f / fmaxf(sqrtf(sk), 1e-12f);
#pragma unroll
  for (int g = 0; g < 2; ++g) {
    U4H pq, pk;
#pragma unroll
    for (int d = 0; d < 4; ++d) {
      int e = g * 8 + 2 * d;
      pq.h[d] = pkrtz(q[e] * rq, q[e + 1] * rq);
      pk.h[d] = pkrtz(k[e] * rk, k[e + 1] * rk);
    }
    qh[(size_t)idx * 2 + g] = pq.u;
    kh[(size_t)idx * 2 + g] = pk.u;
  }
  // V: LDS transpose (256 n  x 16 dims -> 16 rows x 256 n)
#pragma unroll
  for (int d = 0; d < HD; ++d) {
    union { _Float16 f; uint16_t u; } cv;
    cv.f = (_Float16)vv[d];
    lds_v[d * 256 + tid] = cv.u;
  }
  __syncthreads();
  int bh = idx >> 10;                      // block-uniform
  int n0 = (blockIdx.x * 256) & 1023;      // block-uniform
  const uint32_t* ldw = (const uint32_t*)lds_v;
  uint32_t* vtw = (uint32_t*)(vt + (size_t)bh * 16384 + n0);
#pragma unroll
  for (int r = 0; r < 8; ++r) {
    int d = 2 * r + (tid >> 7);
    int c = tid & 127;
    vtw[(size_t)d * 512 + c] = ldw[d * 128 + c];
  }
}

// ---------------- K3: sparse top-k attention via MFMA, 4-wave split-K ----
// (verified round-5 kernel, unchanged)
__global__ __launch_bounds__(256) void k_attn(const uint16_t* __restrict__ qh,
                                              const uint16_t* __restrict__ kh,
                                              const uint16_t* __restrict__ vt,
                                              float* __restrict__ attn_out) {
  __shared__ int cnt_lds[12 * 64];     // [it][lm][w]
  __shared__ float sum_lds[64];        // [lm][w]
  __shared__ f4 obuf[4 * 64];          // [w][lane]
  int tid = threadIdx.x;
  int lane = tid & 63;
  int w = tid >> 6;
  int blk = blockIdx.x;                // 4096 blocks: 64 per (b,h)
  int bh = blk >> 6;
  int q0 = (blk & 63) << 4;
  int lm = lane & 15;
  int lg = lane >> 4;
  int b = bh >> 3, h = bh & 7;

  H4U bq;
  bq.v = *(const h4f*)(qh + ((size_t)bh * 1024 + q0 + lm) * 16 + 4 * lg);
  const h2f qsc = {(_Float16)0.25f, (_Float16)0.25f};
  bq.h[0] *= qsc;
  bq.h[1] *= qsc;

  const f4 z = {0.f, 0.f, 0.f, 0.f};
  const uint16_t* kbase = kh + (size_t)bh * 16384 + 4 * lg;
  h2f sc[16][2];
#pragma unroll
  for (int j = 0; j < 16; ++j) {
    int J = (w << 4) | j;
    h4f ak = *(const h4f*)(kbase + (size_t)(16 * J + lm) * 16); // A[m=krow][k=hd]
    f4 d = __builtin_amdgcn_mfma_f32_16x16x16f16(ak, bq.v, z, 0, 0, 0);
    sc[j][0] = pkrtz(d[0], d[1]);
    sc[j][1] = pkrtz(d[2], d[3]);
  }

  float lo = -0.26f, hi = 0.26f;
  _Float16 hlo = (_Float16)(-0.26f);
#pragma unroll 1
  for (int it = 0; it < 12; ++it) {
    float mid = 0.5f * (lo + hi);
    _Float16 hm = (_Float16)mid;
    int c = 0;
#pragma unroll
    for (int j = 0; j < 16; ++j) {
      c += (sc[j][0][0] >= hm);
      c += (sc[j][0][1] >= hm);
      c += (sc[j][1][0] >= hm);
      c += (sc[j][1][1] >= hm);
    }
    c += __shfl_xor(c, 16);
    c += __shfl_xor(c, 32);
    if (lg == 0) cnt_lds[it * 64 + lm * 4 + w] = c;
    __syncthreads();
    int4 c4 = *(const int4*)&cnt_lds[it * 64 + lm * 4];
    int ct = (c4.x + c4.y) + (c4.z + c4.w);
    bool ge = (ct >= 512);
    lo = ge ? mid : lo;
    hlo = ge ? hm : hlo;
    hi = ge ? hi : mid;
  }

  float ss = 0.f;
#pragma unroll
  for (int j = 0; j < 16; ++j) {
#pragma unroll
    for (int r = 0; r < 2; ++r) {
      h2f t = sc[j][r];
      float p0 = (t[0] >= hlo) ? __expf((float)t[0]) : 0.f;
      float p1 = (t[1] >= hlo) ? __expf((float)t[1]) : 0.f;
      ss += p0 + p1;
      sc[j][r] = pkrtz(p0, p1);
    }
  }
  ss += __shfl_xor(ss, 16);
  ss += __shfl_xor(ss, 32);
  if (lg == 0) sum_lds[lm * 4 + w] = ss;
  __syncthreads();
  float4 s4 = *(const float4*)&sum_lds[lm * 4];
  float inv = 1.f / ((s4.x + s4.y) + (s4.z + s4.w));

  const uint16_t* vbase = vt + (size_t)bh * 16384 + (size_t)lm * 1024 + 4 * lg;
  f4 acc[2] = {z, z};
#pragma unroll
  for (int j = 0; j < 16; ++j) {
    int J = (w << 4) | j;
    h4f va = *(const h4f*)(vbase + 16 * J);   // A[m=dim][k=krow]
    H4U pf;
    pf.h[0] = sc[j][0];
    pf.h[1] = sc[j][1];                        // B[k=krow][n=q]
    acc[j & 1] = __builtin_amdgcn_mfma_f32_16x16x16f16(va, pf.v, acc[j & 1], 0, 0, 0);
  }
  f4 o = acc[0] + acc[1];
  obuf[(w << 6) | lane] = o;
  __syncthreads();
  if (w == 0) {
    f4 t = obuf[lane] + obuf[64 + lane] + obuf[128 + lane] + obuf[192 + lane];
#pragma unroll
    for (int e = 0; e < 4; ++e) {
      int dim = 4 * lg + e;
      attn_out[((size_t)(b * CC + h * HD + dim) * NPIX) + q0 + lm] = t[e] * inv;
    }
  }
}

// ---------------- fused depthwise 3x3 + GN + SiLU ----------------
// grid 256 (b = blk&7, g = blk>>3), 256 threads. Group = 12 ch x 1024 pix.
// LDS stage padded (row stride 36) -> conflict-free stencil reads.
__global__ __launch_bounds__(256) void k_dwgn(const float* __restrict__ in,
                                              const float* __restrict__ w,
                                              float* __restrict__ out,
                                              const float* __restrict__ gamma,
                                              const float* __restrict__ beta) {
  __shared__ float xs[12 * 1152];      // 12 ch x 32 rows x 36 stride = 55.3 KB
  __shared__ float sred[4], s2red[4];
  int blk = blockIdx.x;
  int b = blk & 7, g = blk >> 3;
  int tid = threadIdx.x;
  int c0 = g * 12;
  const float* inb = in + ((size_t)b * C3 + c0) * NPIX;
  // stage: 12288 floats = 12 f4/thread, scatter to padded rows
#pragma unroll
  for (int k = 0; k < 12; ++k) {
    int e = (k * 256 + tid) * 4;
    int cc = e >> 10, rem = e & 1023;
    int row = rem >> 5, col = rem & 31;
    float4 v = *(const float4*)(inb + e);
    *(float4*)&xs[cc * 1152 + row * 36 + col] = v;
  }
  __syncthreads();
  int n0 = tid * 4;
  int i = n0 >> 5, j0 = n0 & 31;
  float acc[12][4];
  float s = 0.f, s2 = 0.f;
#pragma unroll
  for (int cc = 0; cc < 12; ++cc) {
    const float* wc = w + (size_t)(c0 + cc) * 9;
    float w0 = wc[0], w1 = wc[1], w2 = wc[2], w3 = wc[3], w4 = wc[4],
          w5 = wc[5], w6 = wc[6], w7 = wc[7], w8 = wc[8];
    float r[3][6];
#pragma unroll
    for (int di = 0; di < 3; ++di) {
      int ii = i + di - 1;
      bool rv = (ii >= 0 && ii < 32);
#pragma unroll
      for (int dj = 0; dj < 6; ++dj) {
        int jj = j0 + dj - 1;
        r[di][dj] = (rv && jj >= 0 && jj < 32) ? xs[cc * 1152 + ii * 36 + jj] : 0.f;
      }
    }
#pragma unroll
    for (int p = 0; p < 4; ++p) {
      float a = r[0][p] * w0 + r[0][p + 1] * w1 + r[0][p + 2] * w2
              + r[1][p] * w3 + r[1][p + 1] * w4 + r[1][p + 2] * w5
              + r[2][p] * w6 + r[2][p + 1] * w7 + r[2][p + 2] * w8;
      acc[cc][p] = a;
      s += a;
      s2 += a * a;
    }
  }
  // block reduce (4 waves)
#pragma unroll
  for (int off = 32; off > 0; off >>= 1) {
    s += __shfl_xor(s, off);
    s2 += __shfl_xor(s2, off);
  }
  int wv = tid >> 6;
  if ((tid & 63) == 0) { sred[wv] = s; s2red[wv] = s2; }
  __syncthreads();
  float st = sred[0] + sred[1] + sred[2] + sred[3];
  float s2t = s2red[0] + s2red[1] + s2red[2] + s2red[3];
  float inv_n = 1.f / 12288.f;
  float mean = st * inv_n;
  float var = s2t * inv_n - mean * mean;
  float rstd = rsqrtf(var + 1e-6f);
#pragma unroll
  for (int cc = 0; cc < 12; ++cc) {
    float gm = gamma[c0 + cc], bt = beta[c0 + cc];
    float4 o;
    float* op = (float*)&o;
#pragma unroll
    for (int p = 0; p < 4; ++p) {
      float gnv = (acc[cc][p] - mean) * rstd * gm + bt;
      op[p] = gnv / (1.f + __expf(-gnv));   // silu
    }
    *(float4*)(out + ((size_t)b * C3 + c0 + cc) * NPIX + n0) = o;
  }
}

// ---------------- fused pw conv (384->12 of 384) + GN + alpha residual ------
// grid 256 (b = blk&7, g = blk>>3), 256 threads.
__global__ __launch_bounds__(256) void k_pwgn(const float* __restrict__ in,
                                              const float* __restrict__ w,
                                              const float* __restrict__ res,
                                              float* __restrict__ out,
                                              const float* __restrict__ gamma,
                                              const float* __restrict__ beta,
                                              const float* __restrict__ alpha_ptr) {
  __shared__ float wl[12 * 384];   // 18 KB
  __shared__ float sred[4], s2red[4];
  int blk = blockIdx.x;
  int b = blk & 7, g = blk >> 3;
  int tid = threadIdx.x;
  int c0 = g * 12;
  const float* wsrc = w + (size_t)c0 * C3;
  for (int k = tid; k < 12 * 384; k += 256) wl[k] = wsrc[k];
  __syncthreads();
  const float* inb = in + (size_t)b * C3 * NPIX + tid * 4;
  float acc[12][4];
#pragma unroll
  for (int o = 0; o < 12; ++o)
#pragma unroll
    for (int p = 0; p < 4; ++p) acc[o][p] = 0.f;
#pragma unroll 4
  for (int c = 0; c < 384; ++c) {
    float4 v = *(const float4*)(inb + (size_t)c * NPIX);
#pragma unroll
    for (int o = 0; o < 12; ++o) {
      float wv = wl[o * 384 + c];
      acc[o][0] = fmaf(wv, v.x, acc[o][0]);
      acc[o][1] = fmaf(wv, v.y, acc[o][1]);
      acc[o][2] = fmaf(wv, v.z, acc[o][2]);
      acc[o][3] = fmaf(wv, v.w, acc[o][3]);
    }
  }
  float s = 0.f, s2 = 0.f;
#pragma unroll
  for (int o = 0; o < 12; ++o)
#pragma unroll
    for (int p = 0; p < 4; ++p) { s += acc[o][p]; s2 += acc[o][p] * acc[o][p]; }
#pragma unroll
  for (int off = 32; off > 0; off >>= 1) {
    s += __shfl_xor(s, off);
    s2 += __shfl_xor(s2, off);
  }
  int wv = tid >> 6;
  if ((tid & 63) == 0) { sred[wv] = s; s2red[wv] = s2; }
  __syncthreads();
  float st = sred[0] + sred[1] + sred[2] + sred[3];
  float s2t = s2red[0] + s2red[1] + s2red[2] + s2red[3];
  float inv_n = 1.f / 12288.f;
  float mean = st * inv_n;
  float var = s2t * inv_n - mean * mean;
  float rstd = rsqrtf(var + 1e-6f);
  float a = alpha_ptr[0];
#pragma unroll
  for (int o = 0; o < 12; ++o) {
    float gm = gamma[c0 + o], bt = beta[c0 + o];
    size_t base = ((size_t)b * C3 + c0 + o) * NPIX + tid * 4;
    float4 rr = *(const float4*)(res + base);
    float4 ov;
    ov.x = rr.x + a * ((acc[o][0] - mean) * rstd * gm + bt);
    ov.y = rr.y + a * ((acc[o][1] - mean) * rstd * gm + bt);
    ov.z = rr.z + a * ((acc[o][2] - mean) * rstd * gm + bt);
    ov.w = rr.w + a * ((acc[o][3] - mean) * rstd * gm + bt);
    *(float4*)(out + base) = ov;
  }
}

// ---------------- fused ffn conv1 (128->8 of 256) + GN + GELU ----------------
// grid 256 (b = blk&7, g = blk>>3), 512 threads.
__global__ __launch_bounds__(512) void k_ffn1(const float* __restrict__ in,
                                              const float* __restrict__ w,
                                              float* __restrict__ out,
                                              const float* __restrict__ gamma,
                                              const float* __restrict__ beta) {
  __shared__ float wl[8 * 128];    // 4 KB
  __shared__ float sred[8], s2red[8];
  int blk = blockIdx.x;
  int b = blk & 7, g = blk >> 3;
  int tid = threadIdx.x;
  int c0 = g * 8;
  const float* wsrc = w + (size_t)c0 * CC;
  for (int k = tid; k < 8 * 128; k += 512) wl[k] = wsrc[k];
  __syncthreads();
  const float* inb = in + (size_t)b * CC * N4 + tid * 8;
  float acc[8][8];
#pragma unroll
  for (int o = 0; o < 8; ++o)
#pragma unroll
    for (int p = 0; p < 8; ++p) acc[o][p] = 0.f;
#pragma unroll 4
  for (int c = 0; c < 128; ++c) {
    const float* ip = inb + (size_t)c * N4;
    float4 v0 = *(const float4*)ip;
    float4 v1 = *(const float4*)(ip + 4);
#pragma unroll
    for (int o = 0; o < 8; ++o) {
      float wv = wl[o * 128 + c];
      acc[o][0] = fmaf(wv, v0.x, acc[o][0]);
      acc[o][1] = fmaf(wv, v0.y, acc[o][1]);
      acc[o][2] = fmaf(wv, v0.z, acc[o][2]);
      acc[o][3] = fmaf(wv, v0.w, acc[o][3]);
      acc[o][4] = fmaf(wv, v1.x, acc[o][4]);
      acc[o][5] = fmaf(wv, v1.y, acc[o][5]);
      acc[o][6] = fmaf(wv, v1.z, acc[o][6]);
      acc[o][7] = fmaf(wv, v1.w, acc[o][7]);
    }
  }
  float s = 0.f, s2 = 0.f;
#pragma unroll
  for (int o = 0; o < 8; ++o)
#pragma unroll
    for (int p = 0; p < 8; ++p) { s += acc[o][p]; s2 += acc[o][p] * acc[o][p]; }
#pragma unroll
  for (int off = 32; off > 0; off >>= 1) {
    s += __shfl_xor(s, off);
    s2 += __shfl_xor(s2, off);
  }
  int wv = tid >> 6;
  if ((tid & 63) == 0) { sred[wv] = s; s2red[wv] = s2; }
  __syncthreads();
  float st = 0.f, s2t = 0.f;
#pragma unroll
  for (int k = 0; k < 8; ++k) { st += sred[k]; s2t += s2red[k]; }
  float inv_n = 1.f / 32768.f;
  float mean = st * inv_n;
  float var = s2t * inv_n - mean * mean;
  float rstd = rsqrtf(var + 1e-6f);
#pragma unroll
  for (int o = 0; o < 8; ++o) {
    float gm = gamma[c0 + o], bt = beta[c0 + o];
    float r[8];
#pragma unroll
    for (int p = 0; p < 8; ++p) {
      float gnv = (acc[o][p] - mean) * rstd * gm + bt;
      r[p] = 0.5f * gnv * (1.f + erff(gnv * 0.70710678118654752f));  // exact gelu
    }
    float* op = out + ((size_t)(b * 256 + c0 + o)) * N4 + tid * 8;
    *(float4*)op = make_float4(r[0], r[1], r[2], r[3]);
    *(float4*)(op + 4) = make_float4(r[4], r[5], r[6], r[7]);
  }
}

// ---------------- register-cached GN + residual epilogue, 512 thr ----------
template <int ITER, int ACT, bool HAS_RES>
__global__ __launch_bounds__(512) void k_gnr(const float* __restrict__ x,
                                             const float* __restrict__ res,
                                             float* __restrict__ out,
                                             const float* __restrict__ gamma,
                                             const float* __restrict__ beta,
                                             float alpha_const,
                                             int chPerGroup, int Npix, int nshift) {
  int g = blockIdx.x & 31, b = blockIdx.x >> 5;
  int Cout = 32 * chPerGroup;
  int elems = chPerGroup * Npix;
  size_t base = ((size_t)b * Cout + g * chPerGroup) * Npix;
  const float4* xv = (const float4*)(x + base);
  int tid = threadIdx.x;
  float4 xc[ITER];
  float s = 0.f, s2 = 0.f;
#pragma unroll
  for (int k = 0; k < ITER; ++k) {
    float4 v = xv[tid + k * 512];
    xc[k] = v;
    s += v.x + v.y + v.z + v.w;
    s2 += v.x * v.x + v.y * v.y + v.z * v.z + v.w * v.w;
  }
#pragma unroll
  for (int off = 32; off > 0; off >>= 1) {
    s += __shfl_xor(s, off);
    s2 += __shfl_xor(s2, off);
  }
  __shared__ float ls[8], ls2[8];
  int wv = tid >> 6, ln = tid & 63;
  if (ln == 0) { ls[wv] = s; ls2[wv] = s2; }
  __syncthreads();
  float st = 0.f, s2t = 0.f;
#pragma unroll
  for (int k = 0; k < 8; ++k) { st += ls[k]; s2t += ls2[k]; }
  float inv_n = 1.f / (float)elems;
  float mean = st * inv_n;
  float var = s2t * inv_n - mean * mean;
  float rstd = rsqrtf(var + 1e-6f);
  const float4* rv = (const float4*)(res + base);
  float4* ov = (float4*)(out + base);
  int cshift = nshift - 2;
#pragma unroll
  for (int k = 0; k < ITER; ++k) {
    int i = tid + k * 512;
    int cc = g * chPerGroup + (i >> cshift);
    float gm = gamma[cc], bt = beta[cc];
    float4 v = xc[k];
    float r[4] = {v.x, v.y, v.z, v.w};
#pragma unroll
    for (int p = 0; p < 4; ++p) {
      float gnv = (r[p] - mean) * rstd * gm + bt;
      if (ACT == 1)      r[p] = gnv / (1.f + __expf(-gnv));
      else if (ACT == 2) r[p] = 0.5f * gnv * (1.f + erff(gnv * 0.70710678118654752f));
      else               r[p] = gnv;
    }
    float4 o;
    if (HAS_RES) {
      float4 rr = rv[i];
      o = make_float4(rr.x + alpha_const * r[0], rr.y + alpha_const * r[1],
                      rr.z + alpha_const * r[2], rr.w + alpha_const * r[3]);
    } else {
      o = make_float4(r[0], r[1], r[2], r[3]);
    }
    ov[i] = o;
  }
}

// ---------------- K6: IWT + residual ----------------
__global__ __launch_bounds__(256) void k_iwt(const float* __restrict__ x,
                                             const float* __restrict__ s1,
                                             const float* __restrict__ hout,
                                             float* __restrict__ out) {
  int idx = blockIdx.x * 256 + threadIdx.x;  // B*C*32*32
  int w = idx & 31, h = (idx >> 5) & 31, c = (idx >> 10) & 127, b = idx >> 17;
  int n = h * 32 + w;
  float ll = s1[(size_t)(b * CC + c) * NPIX + n];
  float lh = hout[((size_t)b * C3 + c) * NPIX + n];
  float hl = hout[((size_t)b * C3 + CC + c) * NPIX + n];
  float hh = hout[((size_t)b * C3 + 2 * CC + c) * NPIX + n];
  float va = ll - lh - hl + hh;
  float vb = ll - lh + hl - hh;
  float vc = ll + lh - hl - hh;
  float vd = ll + lh + hl + hh;
  size_t xb = ((size_t)(b * CC + c) * HH + 2 * h) * HH + 2 * w;
  out[xb]          = x[xb]          + 0.1f * va;
  out[xb + 1]      = x[xb + 1]      + 0.1f * vc;
  out[xb + HH]     = x[xb + HH]     + 0.1f * vb;
  out[xb + HH + 1] = x[xb + HH + 1] + 0.1f * vd;
}

extern "C" void kernel_launch(void* const* d_in, const int* in_sizes, int n_in,
                              void* d_out, int out_size, void* d_ws, size_t ws_size,
                              hipStream_t stream) {
  const float* x         = (const float*)d_in[0];
  const float* qkv_w     = (const float*)d_in[1];
  const float* proj_w    = (const float*)d_in[2];
  const float* attn_gn_g = (const float*)d_in[3];
  const float* attn_gn_b = (const float*)d_in[4];
  const float* he_dw_w   = (const float*)d_in[5];
  const float* he_gn1_g  = (const float*)d_in[6];
  const float* he_gn1_b  = (const float*)d_in[7];
  const float* he_pw_w   = (const float*)d_in[8];
  const float* he_gn2_g  = (const float*)d_in[9];
  const float* he_gn2_b  = (const float*)d_in[10];
  const float* alpha     = (const float*)d_in[11];
  const float* ffn_w1    = (const float*)d_in[12];
  const float* ffn_gn1_g = (const float*)d_in[13];
  const float* ffn_gn1_b = (const float*)d_in[14];
  const float* ffn_w2    = (const float*)d_in[15];
  const float* ffn_gn2_g = (const float*)d_in[16];
  const float* ffn_gn2_b = (const float*)d_in[17];
  float* out = (float*)d_out;

  float* ws = (float*)d_ws;
  float* ll   = ws;              // 1,048,576
  float* high = ws + 1048576;    // 3,145,728
  float* qkv  = ws + 4194304;    // 3,145,728 ; reused as y1
  float* qnkv = ws + 7340032;    // 3,145,728 ; qh|kh|vt (fp16) ; reused as pw
  float* atto = ws + 10485760;   // 1,048,576
  float* proj = ws + 11534336;   // 1,048,576
  float* f1   = ws + 12582912;   // 8,388,608
  float* f3   = ws + 20971520;   // 4,194,304
  uint4* qh = (uint4*)qnkv;
  uint4* kh = (uint4*)(qnkv + 524288);
  uint16_t* vt = (uint16_t*)(qnkv + 1048576);   // [bh][16][1024] fp16
  float* y1 = qkv;
  float* pw = qnkv;

  // 1) DWT
  k_dwt<<<4096, 256, 0, stream>>>(x, ll, high);
  // 2) qkv = conv1x1(ll, qkv_w); split + l2norm -> packed fp16 (+ V^T)
  k_conv1x1<128, 1, 8><<<dim3(4, 48, 8), 256, 0, stream>>>(ll, qkv_w, qkv, 384, 1024);
  k_qkvnorm<<<256, 256, 0, stream>>>(qkv, qh, kh, vt);
  // 3) sparse attention (MFMA, 4-wave split-K, 16 q-rows per block)
  k_attn<<<4096, 256, 0, stream>>>((const uint16_t*)qh, (const uint16_t*)kh, vt, atto);
  // 4) proj + groupnorm, s1 = ll + gn(proj)
  k_conv1x1<128, 1, 4><<<dim3(4, 32, 8), 256, 0, stream>>>(atto, proj_w, proj, 128, 1024);
  k_gnr<2, 0, true><<<256, 512, 0, stream>>>(proj, ll, proj, attn_gn_g, attn_gn_b,
                                             1.0f, 4, 1024, 10);
  // 5) high enhance: fused dwconv+gn+silu, then fused pw+gn+alpha residual
  k_dwgn<<<256, 256, 0, stream>>>(high, he_dw_w, y1, he_gn1_g, he_gn1_b);
  k_pwgn<<<256, 256, 0, stream>>>(y1, he_pw_w, high, pw, he_gn2_g, he_gn2_b, alpha);
  // 6) IWT + residual -> out
  k_iwt<<<4096, 256, 0, stream>>>(x, proj, pw, out);
  // 7) FFN: fused conv1+gn+gelu, swizzled conv2, reg-cached final gn
  k_ffn1<<<256, 512, 0, stream>>>(out, ffn_w1, f1, ffn_gn1_g, ffn_gn1_b);
  k_conv1x1<256, 4, 8, true><<<512, 256, 0, stream>>>(f1, ffn_w2, f3, 128, 4096);
  k_gnr<8, 0, true><<<256, 512, 0, stream>>>(f3, out, out, ffn_gn2_g, ffn_gn2_b,
                                             0.1f, 4, 4096, 12);
  (void)in_sizes; (void)n_in; (void)out_size; (void)ws_size;
}